// Round 8
// baseline (920.095 us; speedup 1.0000x reference)
//
#include <hip/hip_runtime.h>

#define N_NODES 100000
#define N_EDGES 3200000
static constexpr int NB = (N_NODES + 255) / 256;  // 391
// bucket partition: bucket = dst >> 8 (256 nodes per bucket)
#define NBUK 391   // ceil(N_NODES / 256)
#define NPB 256
#define CHUNK 8192
#define NCHUNK 391  // ceil(N_EDGES / CHUNK); 391*8192 = 3,203,072 >= 3.2M
#define GSB 2048   // grid-stride blocks for node-parallel kernels (launch-rate fix)

__device__ __forceinline__ float bf2f(unsigned short u) {
  return __uint_as_float(((unsigned)u) << 16);
}
__device__ __forceinline__ unsigned short f2bf(float f) {
  unsigned u = __float_as_uint(f);
  u += 0x7fffu + ((u >> 16) & 1u);
  return (unsigned short)(u >> 16);
}
__device__ __forceinline__ float lo16(unsigned u) { return __uint_as_float(u << 16); }
__device__ __forceinline__ float hi16(unsigned u) { return __uint_as_float(u & 0xffff0000u); }

// ---------------- dtype detection (flag=1: bf16 storage, 0: fp32) ----------------

__global__ void k_detect(const unsigned short* __restrict__ xu, int* __restrict__ flag) {
  __shared__ int cnt;
  if (threadIdx.x == 0) cnt = 0;
  __syncthreads();
  int c = 0;
  for (int i = threadIdx.x; i < 4096; i += 256) {
    float v = fabsf(bf2f(xu[2 * i]));
    if (v >= 1e-4f && v <= 10.f) c++;
  }
  atomicAdd(&cnt, c);
  __syncthreads();
  if (threadIdx.x == 0) *flag = (cnt > 2048) ? 1 : 0;
}

// ---------------- canonicalize inputs to bf16 ----------------

__global__ __launch_bounds__(512) void k_cvt_x(const void* __restrict__ x,
                                               unsigned short* __restrict__ xb,
                                               const int* __restrict__ flag) {
  int i = blockIdx.x * 512 + threadIdx.x;  // one uint4 (8 bf16) per thread
  if (i >= N_NODES * 8) return;
  if (*flag) {
    ((uint4*)xb)[i] = ((const uint4*)x)[i];
  } else {
    const float4* xf = (const float4*)x;
    float4 a = xf[2 * i], b = xf[2 * i + 1];
    uint4 o;
    o.x = (unsigned)f2bf(a.x) | ((unsigned)f2bf(a.y) << 16);
    o.y = (unsigned)f2bf(a.z) | ((unsigned)f2bf(a.w) << 16);
    o.z = (unsigned)f2bf(b.x) | ((unsigned)f2bf(b.y) << 16);
    o.w = (unsigned)f2bf(b.z) | ((unsigned)f2bf(b.w) << 16);
    ((uint4*)xb)[i] = o;
  }
}

struct CvtArgs {
  const void* src[24];
  int dstoff[24];
  int n[24];
  int stride[24];
};

__global__ void k_cvt_w(CvtArgs a, unsigned short* __restrict__ wb,
                        const int* __restrict__ flag) {
  int b = blockIdx.x;
  const void* s = a.src[b];
  int n = a.n[b];
  int st = a.stride[b];
  unsigned short* d = wb + a.dstoff[b];
  int isbf = *flag;
  for (int i = threadIdx.x; i < n; i += 256)
    d[i * st] = isbf ? ((const unsigned short*)s)[i] : f2bf(((const float*)s)[i]);
}

// ---------------- CSR build: two-level bucket partition ----------------

// A1: per-chunk bucket histogram
__global__ __launch_bounds__(256) void k_bhist(const int* __restrict__ dsts,
                                               int* __restrict__ counts) {
  __shared__ int hist[NBUK];
  for (int i = threadIdx.x; i < NBUK; i += 256) hist[i] = 0;
  __syncthreads();
  int e0 = blockIdx.x * CHUNK;
  int n = min(CHUNK, N_EDGES - e0);
  for (int i = threadIdx.x; i < n; i += 256)
    atomicAdd(&hist[dsts[e0 + i] >> 8], 1);
  __syncthreads();
  for (int i = threadIdx.x; i < NBUK; i += 256)
    counts[blockIdx.x * NBUK + i] = hist[i];  // chunk-major
}

// A2a: per-bucket exclusive prefix over chunks (one wave per bucket) + total
__global__ __launch_bounds__(64) void k_bscanA(int* __restrict__ counts,
                                               int* __restrict__ tot) {
  int b = blockIdx.x;
  int lane = threadIdx.x;
  int carry = 0;
  for (int c0 = 0; c0 < NCHUNK; c0 += 64) {
    int c = c0 + lane;
    int v = (c < NCHUNK) ? counts[c * NBUK + b] : 0;
    int s = v;
#pragma unroll
    for (int o = 1; o < 64; o <<= 1) {
      int u = __shfl_up(s, o, 64);
      if (lane >= o) s += u;
    }
    if (c < NCHUNK) counts[c * NBUK + b] = s - v + carry;  // bucket-local base
    carry += __shfl(s, 63, 64);
  }
  if (lane == 0) tot[b] = carry;
}

// A2b: scan bucket totals -> bbase
__global__ void k_bscanB(const int* __restrict__ tot, int* __restrict__ bbase) {
  __shared__ int s[512];
  int t = threadIdx.x;
  int v = (t < NBUK) ? tot[t] : 0;
  s[t] = v;
  __syncthreads();
  for (int o = 1; o < 512; o <<= 1) {
    int u = (t >= o) ? s[t - o] : 0;
    __syncthreads();
    s[t] += u;
    __syncthreads();
  }
  if (t <= NBUK) bbase[t] = s[t] - v;  // v==0 for t==NBUK -> total
}

// A3: rank-scatter packed (src<<8 | dst&255) into bucket-grouped list.
// bbase add folded in here (was a separate k_bscanC pass).
__global__ __launch_bounds__(256) void k_bscat(const int* __restrict__ srcs,
                                               const int* __restrict__ dsts,
                                               const int* __restrict__ counts,
                                               const int* __restrict__ bbase,
                                               unsigned* __restrict__ blist) {
  __shared__ int cnt[NBUK];
  for (int i = threadIdx.x; i < NBUK; i += 256)
    cnt[i] = counts[blockIdx.x * NBUK + i] + bbase[i];
  __syncthreads();
  int e0 = blockIdx.x * CHUNK;
  int n = min(CHUNK, N_EDGES - e0);
  for (int i = threadIdx.x; i < n; i += 256) {
    int s = srcs[e0 + i];
    int d = dsts[e0 + i];
    int p = atomicAdd(&cnt[d >> 8], 1);
    blist[p] = ((unsigned)s << 8) | (unsigned)(d & 255);
  }
}

// B: fused per-bucket degree + scan + offset write + csr fill.
__global__ __launch_bounds__(256) void k_bfinal(const unsigned* __restrict__ blist,
                                                const int* __restrict__ bbase,
                                                int* __restrict__ off,
                                                int* __restrict__ csr) {
  __shared__ int hcnt[NPB];
  __shared__ int sc[NPB];
  int t = threadIdx.x;
  int b = blockIdx.x;
  int s = bbase[b], e = bbase[b + 1];
  hcnt[t] = 0;
  __syncthreads();
  for (int i = s + t; i < e; i += 256)
    atomicAdd(&hcnt[blist[i] & 255], 1);
  __syncthreads();
  int v = hcnt[t];
  sc[t] = v;
  __syncthreads();
  for (int o = 1; o < 256; o <<= 1) {
    int u = (t >= o) ? sc[t - o] : 0;
    __syncthreads();
    sc[t] += u;
    __syncthreads();
  }
  int my = s + sc[t] - v;  // global csr offset of this node
  int node = b * NPB + t;
  if (node < N_NODES) off[node] = my;
  if (b == 0 && t == 0) off[N_NODES] = bbase[NBUK];
  sc[t] = my;  // becomes the scatter cursor
  __syncthreads();
  for (int i = s + t; i < e; i += 256) {
    unsigned u = blist[i];
    int p = atomicAdd(&sc[u & 255], 1);
    csr[p] = (int)(u >> 8);
  }
}

// ---------------- K,V projection (fallback path, small workspace) ----------------

__global__ __launch_bounds__(256) void k_gemmkv(
    const unsigned short* __restrict__ hin,
    const unsigned* __restrict__ PKV,  // lo=Wk, hi=Wv, [k*64+lane]
    const unsigned short* __restrict__ bk, const unsigned short* __restrict__ bv,
    unsigned short* __restrict__ Kt, unsigned short* __restrict__ Vt) {
  int r = blockIdx.x * 4 + (threadIdx.x >> 6);
  int lane = threadIdx.x & 63;
  float hv = bf2f(hin[(size_t)r * 64 + lane]);
  float ka = bf2f(bk[lane]);
  float va = bf2f(bv[lane]);
  for (int k = 0; k < 64; ++k) {
    float hk = __shfl(hv, k, 64);
    unsigned u = PKV[k * 64 + lane];
    ka += hk * lo16(u);
    va += hk * hi16(u);
  }
  Kt[(size_t)r * 64 + lane] = f2bf(ka);
  Vt[(size_t)r * 64 + lane] = f2bf(va);
}

// ---------------- fused K,V,Q,S projection (big-ws), grid-stride ----------------
// 25K-WG launches were command-processor-bound (~200 WG/us): every 25K-block
// kernel had a ~125us dispatch floor. 2048 blocks x 8 waves, wave strides
// over rows; per-row arithmetic identical.

__global__ __launch_bounds__(512) void k_gemmkvqs(
    const unsigned short* __restrict__ hin,
    const unsigned* __restrict__ PKV, const unsigned* __restrict__ PQS,
    const unsigned short* __restrict__ bk, const unsigned short* __restrict__ bv,
    const unsigned short* __restrict__ bq, const unsigned short* __restrict__ bs,
    unsigned short* __restrict__ Kt, unsigned short* __restrict__ Vt,
    float* __restrict__ Qt, float* __restrict__ St) {
  int w = threadIdx.x >> 6;
  int lane = threadIdx.x & 63;
  for (int r = blockIdx.x * 8 + w; r < N_NODES; r += gridDim.x * 8) {
    float hv = bf2f(hin[(size_t)r * 64 + lane]);
    float ka = bf2f(bk[lane]);
    float va = bf2f(bv[lane]);
    float qa = bf2f(bq[lane]);
    float sa = bf2f(bs[lane]);
    for (int k = 0; k < 64; ++k) {
      float hk = __shfl(hv, k, 64);
      unsigned u = PKV[k * 64 + lane];
      unsigned u2 = PQS[k * 64 + lane];
      ka += hk * lo16(u);
      va += hk * hi16(u);
      qa += hk * lo16(u2);
      sa += hk * hi16(u2);
    }
    Kt[(size_t)r * 64 + lane] = f2bf(ka);
    Vt[(size_t)r * 64 + lane] = f2bf(va);
    Qt[(size_t)r * 64 + lane] = qa;
    St[(size_t)r * 64 + lane] = sa;
  }
}

// ---------------- edge pass, C=64 (fallback: projection in-kernel) ----------------
// Best measured small-ws config: 250 µs @ 68 VGPR. Do NOT add register
// pressure or min-waves bounds (measured: 92 VGPR -> 289us; forced bounds ->
// 32 VGPR + full spill -> 622us).

template <bool RES>
__global__ __launch_bounds__(256) void k_edge64(
    const int* __restrict__ off, const int* __restrict__ csr,
    const unsigned short* __restrict__ hin,
    const unsigned* __restrict__ PQS,  // lo=Wq, hi=Ws, [k*64+lane]
    const unsigned short* __restrict__ bq, const unsigned short* __restrict__ bs,
    const unsigned short* __restrict__ Kt, const unsigned short* __restrict__ Vt,
    unsigned short* __restrict__ hout) {
  __shared__ float qs[4][64];
  int w = threadIdx.x >> 6;
  int lane = threadIdx.x & 63;
  int wid = blockIdx.x * 4 + w;
  int base = off[wid];
  int deg = off[wid + 1] - base;
  int nsrc = csr[base + ((lane < deg) ? lane : 0)];
  float hv = bf2f(hin[(size_t)wid * 64 + lane]);
  float q = bf2f(bq[lane]);
  float sk = bf2f(bs[lane]);
  for (int k = 0; k < 64; ++k) {
    float hk = __shfl(hv, k, 64);
    unsigned uw = PQS[k * 64 + lane];
    q += hk * lo16(uw);
    sk += hk * hi16(uw);
  }
  qs[w][lane] = q;

  float m = -1e30f, ssum = 0.f;
  float4 acc = {0.f, 0.f, 0.f, 0.f};
  int g = lane >> 4;
  int c16 = lane & 15;
  const float4* qv = (const float4*)qs[w];

  for (int j0 = 0; j0 < deg; j0 += 64) {
    int cnt = min(64, deg - j0);
    int src = nsrc;
    int nj = j0 + 64;
    if (nj < deg)
      nsrc = csr[base + nj + ((lane < deg - nj) ? lane : 0)];
    const uint4* kp = (const uint4*)(Kt + (size_t)src * 64);
    float d0 = 0.f, d1 = 0.f, d2 = 0.f, d3 = 0.f;
#pragma unroll
    for (int i = 0; i < 8; ++i) {
      uint4 kk = kp[i];
      float4 qa = qv[2 * i];
      float4 qb = qv[2 * i + 1];
      d0 += qa.x * lo16(kk.x); d1 += qa.y * hi16(kk.x);
      d2 += qa.z * lo16(kk.y); d3 += qa.w * hi16(kk.y);
      d0 += qb.x * lo16(kk.z); d1 += qb.y * hi16(kk.z);
      d2 += qb.z * lo16(kk.w); d3 += qb.w * hi16(kk.w);
    }
    float sc = ((d0 + d1) + (d2 + d3)) * 0.125f;
    sc = fminf(fmaxf(sc, -60.f), 60.f);
    if (lane >= cnt) sc = -1e30f;
    float bm = sc;
    bm = fmaxf(bm, __shfl_xor(bm, 32, 64));
    bm = fmaxf(bm, __shfl_xor(bm, 16, 64));
    bm = fmaxf(bm, __shfl_xor(bm, 8, 64));
    bm = fmaxf(bm, __shfl_xor(bm, 4, 64));
    bm = fmaxf(bm, __shfl_xor(bm, 2, 64));
    bm = fmaxf(bm, __shfl_xor(bm, 1, 64));
    float mn = fmaxf(m, bm);
    float al = __expf(sc - mn);
    float bsum = al;
    bsum += __shfl_xor(bsum, 32, 64);
    bsum += __shfl_xor(bsum, 16, 64);
    bsum += __shfl_xor(bsum, 8, 64);
    bsum += __shfl_xor(bsum, 4, 64);
    bsum += __shfl_xor(bsum, 2, 64);
    bsum += __shfl_xor(bsum, 1, 64);
    float corr = __expf(m - mn);
    ssum = ssum * corr + bsum;
    acc.x *= corr;
    acc.y *= corr;
    acc.z *= corr;
    acc.w *= corr;
    m = mn;
    for (int jj = 0; jj < cnt; jj += 16) {
      int e0 = jj + g, e1 = jj + 4 + g, e2 = jj + 8 + g, e3 = jj + 12 + g;
      int s0 = __shfl(src, e0, 64);
      int s1 = __shfl(src, e1, 64);
      int s2 = __shfl(src, e2, 64);
      int s3 = __shfl(src, e3, 64);
      float a0 = __shfl(al, e0, 64);
      float a1 = __shfl(al, e1, 64);
      float a2 = __shfl(al, e2, 64);
      float a3 = __shfl(al, e3, 64);
      uint2 v0 = *(const uint2*)(Vt + (size_t)s0 * 64 + c16 * 4);
      uint2 v1 = *(const uint2*)(Vt + (size_t)s1 * 64 + c16 * 4);
      uint2 v2 = *(const uint2*)(Vt + (size_t)s2 * 64 + c16 * 4);
      uint2 v3 = *(const uint2*)(Vt + (size_t)s3 * 64 + c16 * 4);
      acc.x += a0 * lo16(v0.x); acc.y += a0 * hi16(v0.x);
      acc.z += a0 * lo16(v0.y); acc.w += a0 * hi16(v0.y);
      acc.x += a1 * lo16(v1.x); acc.y += a1 * hi16(v1.x);
      acc.z += a1 * lo16(v1.y); acc.w += a1 * hi16(v1.y);
      acc.x += a2 * lo16(v2.x); acc.y += a2 * hi16(v2.x);
      acc.z += a2 * lo16(v2.y); acc.w += a2 * hi16(v2.y);
      acc.x += a3 * lo16(v3.x); acc.y += a3 * hi16(v3.x);
      acc.z += a3 * lo16(v3.y); acc.w += a3 * hi16(v3.y);
    }
  }
  acc.x += __shfl_xor(acc.x, 16, 64);
  acc.y += __shfl_xor(acc.y, 16, 64);
  acc.z += __shfl_xor(acc.z, 16, 64);
  acc.w += __shfl_xor(acc.w, 16, 64);
  acc.x += __shfl_xor(acc.x, 32, 64);
  acc.y += __shfl_xor(acc.y, 32, 64);
  acc.z += __shfl_xor(acc.z, 32, 64);
  acc.w += __shfl_xor(acc.w, 32, 64);
  float f0 = __shfl(acc.x, lane >> 2, 64);
  float f1 = __shfl(acc.y, lane >> 2, 64);
  float f2 = __shfl(acc.z, lane >> 2, 64);
  float f3 = __shfl(acc.w, lane >> 2, 64);
  int cc = lane & 3;
  float aggv = (cc == 0) ? f0 : ((cc == 1) ? f1 : ((cc == 2) ? f2 : f3));
  float val = aggv / (ssum + 1e-16f) + sk;
  if (RES) val += hv;
  hout[(size_t)wid * 64 + lane] = f2bf(tanhf(val));
}

// ---------------- edge pass, C=64, big-ws: grid-stride 8-wave blocks ----------------
// Per-dst computation identical to round-7 k_edge64b; only dst->wave
// assignment changed (wave strides over ~6 dsts).

template <bool RES>
__global__ __launch_bounds__(512) void k_edge64b(
    const int* __restrict__ off, const int* __restrict__ csr,
    const unsigned short* __restrict__ hin,
    const float* __restrict__ Qt, const float* __restrict__ St,
    const unsigned short* __restrict__ Kt, const unsigned short* __restrict__ Vt,
    unsigned short* __restrict__ hout) {
  __shared__ float qs[8][64];
  int w = threadIdx.x >> 6;
  int lane = threadIdx.x & 63;
  int g = lane >> 4;
  int c16 = lane & 15;
  const float4* qv = (const float4*)qs[w];

  for (int wid = blockIdx.x * 8 + w; wid < N_NODES; wid += gridDim.x * 8) {
    int base = off[wid];
    int deg = off[wid + 1] - base;
    int nsrc = csr[base + ((lane < deg) ? lane : 0)];
    float q = Qt[(size_t)wid * 64 + lane];
    float sk = St[(size_t)wid * 64 + lane];
    float hv = 0.f;
    if (RES) hv = bf2f(hin[(size_t)wid * 64 + lane]);
    qs[w][lane] = q;  // wave-local write->read; lgkmcnt ordering within wave

    float m = -1e30f, ssum = 0.f;
    float4 acc = {0.f, 0.f, 0.f, 0.f};

    for (int j0 = 0; j0 < deg; j0 += 64) {
      int cnt = min(64, deg - j0);
      int src = nsrc;
      int nj = j0 + 64;
      if (nj < deg)
        nsrc = csr[base + nj + ((lane < deg - nj) ? lane : 0)];
      const uint4* kp = (const uint4*)(Kt + (size_t)src * 64);
      float d0 = 0.f, d1 = 0.f, d2 = 0.f, d3 = 0.f;
#pragma unroll
      for (int i = 0; i < 8; ++i) {
        uint4 kk = kp[i];
        float4 qa = qv[2 * i];
        float4 qb = qv[2 * i + 1];
        d0 += qa.x * lo16(kk.x); d1 += qa.y * hi16(kk.x);
        d2 += qa.z * lo16(kk.y); d3 += qa.w * hi16(kk.y);
        d0 += qb.x * lo16(kk.z); d1 += qb.y * hi16(kk.z);
        d2 += qb.z * lo16(kk.w); d3 += qb.w * hi16(kk.w);
      }
      float sc = ((d0 + d1) + (d2 + d3)) * 0.125f;
      sc = fminf(fmaxf(sc, -60.f), 60.f);
      if (lane >= cnt) sc = -1e30f;
      float bm = sc;
      bm = fmaxf(bm, __shfl_xor(bm, 32, 64));
      bm = fmaxf(bm, __shfl_xor(bm, 16, 64));
      bm = fmaxf(bm, __shfl_xor(bm, 8, 64));
      bm = fmaxf(bm, __shfl_xor(bm, 4, 64));
      bm = fmaxf(bm, __shfl_xor(bm, 2, 64));
      bm = fmaxf(bm, __shfl_xor(bm, 1, 64));
      float mn = fmaxf(m, bm);
      float al = __expf(sc - mn);
      float bsum = al;
      bsum += __shfl_xor(bsum, 32, 64);
      bsum += __shfl_xor(bsum, 16, 64);
      bsum += __shfl_xor(bsum, 8, 64);
      bsum += __shfl_xor(bsum, 4, 64);
      bsum += __shfl_xor(bsum, 2, 64);
      bsum += __shfl_xor(bsum, 1, 64);
      float corr = __expf(m - mn);
      ssum = ssum * corr + bsum;
      acc.x *= corr;
      acc.y *= corr;
      acc.z *= corr;
      acc.w *= corr;
      m = mn;
      for (int jj = 0; jj < cnt; jj += 16) {
        int e0 = jj + g, e1 = jj + 4 + g, e2 = jj + 8 + g, e3 = jj + 12 + g;
        int s0 = __shfl(src, e0, 64);
        int s1 = __shfl(src, e1, 64);
        int s2 = __shfl(src, e2, 64);
        int s3 = __shfl(src, e3, 64);
        float a0 = __shfl(al, e0, 64);
        float a1 = __shfl(al, e1, 64);
        float a2 = __shfl(al, e2, 64);
        float a3 = __shfl(al, e3, 64);
        uint2 v0 = *(const uint2*)(Vt + (size_t)s0 * 64 + c16 * 4);
        uint2 v1 = *(const uint2*)(Vt + (size_t)s1 * 64 + c16 * 4);
        uint2 v2 = *(const uint2*)(Vt + (size_t)s2 * 64 + c16 * 4);
        uint2 v3 = *(const uint2*)(Vt + (size_t)s3 * 64 + c16 * 4);
        acc.x += a0 * lo16(v0.x); acc.y += a0 * hi16(v0.x);
        acc.z += a0 * lo16(v0.y); acc.w += a0 * hi16(v0.y);
        acc.x += a1 * lo16(v1.x); acc.y += a1 * hi16(v1.x);
        acc.z += a1 * lo16(v1.y); acc.w += a1 * hi16(v1.y);
        acc.x += a2 * lo16(v2.x); acc.y += a2 * hi16(v2.x);
        acc.z += a2 * lo16(v2.y); acc.w += a2 * hi16(v2.y);
        acc.x += a3 * lo16(v3.x); acc.y += a3 * hi16(v3.x);
        acc.z += a3 * lo16(v3.y); acc.w += a3 * hi16(v3.y);
      }
    }
    acc.x += __shfl_xor(acc.x, 16, 64);
    acc.y += __shfl_xor(acc.y, 16, 64);
    acc.z += __shfl_xor(acc.z, 16, 64);
    acc.w += __shfl_xor(acc.w, 16, 64);
    acc.x += __shfl_xor(acc.x, 32, 64);
    acc.y += __shfl_xor(acc.y, 32, 64);
    acc.z += __shfl_xor(acc.z, 32, 64);
    acc.w += __shfl_xor(acc.w, 32, 64);
    float f0 = __shfl(acc.x, lane >> 2, 64);
    float f1 = __shfl(acc.y, lane >> 2, 64);
    float f2 = __shfl(acc.z, lane >> 2, 64);
    float f3 = __shfl(acc.w, lane >> 2, 64);
    int cc = lane & 3;
    float aggv = (cc == 0) ? f0 : ((cc == 1) ? f1 : ((cc == 2) ? f2 : f3));
    float val = aggv / (ssum + 1e-16f) + sk;
    if (RES) val += hv;
    hout[(size_t)wid * 64 + lane] = f2bf(tanhf(val));
  }
}

// ---------------- layer 3 projections (C=3): wave per node, grid-stride ----------------

__global__ __launch_bounds__(512) void k_gemm3(
    const unsigned short* __restrict__ hin,
    const unsigned short* __restrict__ Wq, const unsigned short* __restrict__ bq,
    const unsigned short* __restrict__ Wk, const unsigned short* __restrict__ bk,
    const unsigned short* __restrict__ Wv, const unsigned short* __restrict__ bv,
    const unsigned short* __restrict__ Ws, const unsigned short* __restrict__ bs,
    float* __restrict__ Q3, float* __restrict__ S3, uint4* __restrict__ KV3) {
  int w = threadIdx.x >> 6;
  int lane = threadIdx.x & 63;
  for (int r = blockIdx.x * 8 + w; r < N_NODES; r += gridDim.x * 8) {
    float hj = bf2f(hin[(size_t)r * 64 + lane]);
    float p[12];
#pragma unroll
    for (int c = 0; c < 3; ++c) {
      p[c]     = hj * bf2f(Wq[lane * 3 + c]);
      p[3 + c] = hj * bf2f(Wk[lane * 3 + c]);
      p[6 + c] = hj * bf2f(Wv[lane * 3 + c]);
      p[9 + c] = hj * bf2f(Ws[lane * 3 + c]);
    }
#pragma unroll
    for (int o = 32; o >= 1; o >>= 1) {
#pragma unroll
      for (int i = 0; i < 12; ++i) p[i] += __shfl_xor(p[i], o, 64);
    }
    if (lane == 0) {
      float kk[3], vv[3];
      for (int c = 0; c < 3; ++c) {
        Q3[r * 4 + c] = p[c] + bf2f(bq[c]);
        S3[r * 4 + c] = p[9 + c] + bf2f(bs[c]);
        kk[c] = p[3 + c] + bf2f(bk[c]);
        vv[c] = p[6 + c] + bf2f(bv[c]);
      }
      uint4 pk;
      pk.x = (unsigned)f2bf(kk[0]) | ((unsigned)f2bf(vv[0]) << 16);
      pk.y = (unsigned)f2bf(kk[1]) | ((unsigned)f2bf(vv[1]) << 16);
      pk.z = (unsigned)f2bf(kk[2]) | ((unsigned)f2bf(vv[2]) << 16);
      pk.w = 0;
      KV3[r] = pk;
    }
  }
}

// ---------------- edge pass, C=3: wave per dst, grid-stride ----------------

__global__ __launch_bounds__(512) void k_edge3(
    const int* __restrict__ off, const int* __restrict__ csr,
    const float* __restrict__ Q3, const float* __restrict__ S3,
    const uint4* __restrict__ KV3, const void* __restrict__ noise,
    void* __restrict__ out, const int* __restrict__ flag) {
  int w = threadIdx.x >> 6;
  int lane = threadIdx.x & 63;
  for (int d = blockIdx.x * 8 + w; d < N_NODES; d += gridDim.x * 8) {
    int base = off[d];
    int deg = off[d + 1] - base;
    float q0 = Q3[d * 4], q1 = Q3[d * 4 + 1], q2 = Q3[d * 4 + 2];
    const float isq = 0.57735026919f;  // 1/sqrt(3)
    float m = -1e30f, ssum = 0.f, a0 = 0.f, a1 = 0.f, a2 = 0.f;
    for (int j0 = 0; j0 < deg; j0 += 64) {
      int cnt = min(64, deg - j0);
      int src = csr[base + ((lane < cnt) ? (j0 + lane) : 0)];
      uint4 kv = KV3[src];
      float sc = (q0 * lo16(kv.x) + q1 * lo16(kv.y) + q2 * lo16(kv.z)) * isq;
      sc = fminf(fmaxf(sc, -60.f), 60.f);
      if (lane >= cnt) sc = -1e30f;
      float bm = sc;
#pragma unroll
      for (int o = 32; o >= 1; o >>= 1) bm = fmaxf(bm, __shfl_xor(bm, o, 64));
      float mn = fmaxf(m, bm);
      float al = __expf(sc - mn);  // inactive lanes -> 0
      float p0 = al * hi16(kv.x);
      float p1 = al * hi16(kv.y);
      float p2 = al * hi16(kv.z);
      float bsum = al;
#pragma unroll
      for (int o = 32; o >= 1; o >>= 1) {
        bsum += __shfl_xor(bsum, o, 64);
        p0 += __shfl_xor(p0, o, 64);
        p1 += __shfl_xor(p1, o, 64);
        p2 += __shfl_xor(p2, o, 64);
      }
      float corr = __expf(m - mn);
      ssum = ssum * corr + bsum;
      a0 = a0 * corr + p0;
      a1 = a1 * corr + p1;
      a2 = a2 * corr + p2;
      m = mn;
    }
    if (lane == 0) {
      float inv = 1.f / (ssum + 1e-16f);
      int isbf = *flag;
      float n0, n1, n2;
      if (isbf) {
        const unsigned short* nu = (const unsigned short*)noise;
        n0 = bf2f(nu[d * 3 + 0]);
        n1 = bf2f(nu[d * 3 + 1]);
        n2 = bf2f(nu[d * 3 + 2]);
      } else {
        const float* nf = (const float*)noise;
        n0 = nf[d * 3 + 0];
        n1 = nf[d * 3 + 1];
        n2 = nf[d * 3 + 2];
      }
      float r0 = a0 * inv + S3[d * 4 + 0] + 0.1f * n0;
      float r1 = a1 * inv + S3[d * 4 + 1] + 0.1f * n1;
      float r2 = a2 * inv + S3[d * 4 + 2] + 0.1f * n2;
      if (isbf) {
        unsigned short* ou = (unsigned short*)out;
        ou[d * 3 + 0] = f2bf(r0);
        ou[d * 3 + 1] = f2bf(r1);
        ou[d * 3 + 2] = f2bf(r2);
      } else {
        float* of = (float*)out;
        of[d * 3 + 0] = r0;
        of[d * 3 + 1] = r1;
        of[d * 3 + 2] = r2;
      }
    }
  }
}

// ---------------- launch ----------------

extern "C" void kernel_launch(void* const* d_in, const int* in_sizes, int n_in,
                              void* d_out, int out_size, void* d_ws, size_t ws_size,
                              hipStream_t stream) {
  const int* ei = (const int*)d_in[1];
  const int* srcs = ei;
  const int* dsts = ei + N_EDGES;

  // Workspace base layout (NEED = 51668480 B, proven available):
  //   off @0 | csr @400128 | h @13200128 (bf16; CSR-build scratch aliased)
  //   kvbase @26000128: blist during build; then Kt/Vt bf16; Q3/S3/KV3 layer 3
  //   wb @51600128 | flag @51668352
  // Extended layout (if ws_size >= NEED_BIG = 102868480):
  //   Qt f32 [N][64] @51668480 (25.6MB) | St f32 @77268480 (25.6MB)
  char* w = (char*)d_ws;
  int* off = (int*)w;
  int* csr = (int*)(w + 400128);
  char* hreg = w + 13200128;
  unsigned short* h = (unsigned short*)hreg;
  int* counts = (int*)(hreg + 524288);   // NCHUNK*NBUK ints = 611,524 B
  int* bbase = (int*)(hreg + 1200128);   // NBUK+1 ints
  int* tot = (int*)(hreg + 1310720);     // NBUK ints
  char* kvbase = w + 26000128;
  unsigned* blist = (unsigned*)kvbase;
  unsigned short* Kt = (unsigned short*)kvbase;
  unsigned short* Vt = (unsigned short*)(kvbase + 12800000);
  float* Q3 = (float*)kvbase;
  float* S3 = (float*)(kvbase + 2097152);
  uint4* KV3 = (uint4*)(kvbase + 4194304);
  unsigned short* wb = (unsigned short*)(w + 51600128);
  int* flag = (int*)(w + 51668352);
  float* Qt = (float*)(w + 51668480);
  float* St = (float*)(w + 77268480);
  const size_t NEED = 51668480;
  const size_t NEED_BIG = 102868480;
  if (ws_size < NEED) return;
  const bool big = (ws_size >= NEED_BIG);

  CvtArgs ca;
  {
    int idx = 0;
    const int moff[4] = {0, 8192, 8193, 1};  // q,k,v,s matrix dst offsets (shorts)
    const int boff[4] = {16384, 16448, 16512, 16576};
    for (int l = 0; l < 2; ++l) {
      int base = l * 16640;
      for (int p = 0; p < 4; ++p) {
        ca.src[idx] = d_in[3 + l * 8 + p * 2];
        ca.dstoff[idx] = base + moff[p];
        ca.n[idx] = 4096;
        ca.stride[idx] = 2;
        idx++;
        ca.src[idx] = d_in[3 + l * 8 + p * 2 + 1];
        ca.dstoff[idx] = base + boff[p];
        ca.n[idx] = 64;
        ca.stride[idx] = 1;
        idx++;
      }
    }
    int o = 33280;  // layer 3, stride-1
    for (int p = 0; p < 4; ++p) {
      ca.src[idx] = d_in[3 + 16 + p * 2];
      ca.dstoff[idx] = o;
      ca.n[idx] = 192;
      ca.stride[idx] = 1;
      o += 192;
      idx++;
      ca.src[idx] = d_in[3 + 16 + p * 2 + 1];
      ca.dstoff[idx] = o;
      ca.n[idx] = 3;
      ca.stride[idx] = 1;
      o += 3;
      idx++;
    }
  }
  const unsigned* PQS0 = (const unsigned*)(wb);
  const unsigned* PKV0 = (const unsigned*)(wb + 8192);
  const unsigned* PQS1 = (const unsigned*)(wb + 16640);
  const unsigned* PKV1 = (const unsigned*)(wb + 16640 + 8192);
  const unsigned short* Bq0 = wb + 16384;
  const unsigned short* Bk0 = wb + 16448;
  const unsigned short* Bv0 = wb + 16512;
  const unsigned short* Bs0 = wb + 16576;
  const unsigned short* Bq1 = wb + 16640 + 16384;
  const unsigned short* Bk1 = wb + 16640 + 16448;
  const unsigned short* Bv1 = wb + 16640 + 16512;
  const unsigned short* Bs1 = wb + 16640 + 16576;
  const unsigned short* W3q = wb + 33280;
  const unsigned short* B3q = wb + 33472;
  const unsigned short* W3k = wb + 33475;
  const unsigned short* B3k = wb + 33667;
  const unsigned short* W3v = wb + 33670;
  const unsigned short* B3v = wb + 33862;
  const unsigned short* W3s = wb + 33865;
  const unsigned short* B3s = wb + 34057;

  k_detect<<<1, 256, 0, stream>>>((const unsigned short*)d_in[0], flag);
  k_cvt_w<<<24, 256, 0, stream>>>(ca, wb, flag);

  // CSR build (uses hreg + kvbase as scratch; must precede k_cvt_x)
  k_bhist<<<NCHUNK, 256, 0, stream>>>(dsts, counts);
  k_bscanA<<<NBUK, 64, 0, stream>>>(counts, tot);
  k_bscanB<<<1, 512, 0, stream>>>(tot, bbase);
  k_bscat<<<NCHUNK, 256, 0, stream>>>(srcs, dsts, counts, bbase, blist);
  k_bfinal<<<NBUK, 256, 0, stream>>>(blist, bbase, off, csr);

  k_cvt_x<<<(N_NODES * 8 + 511) / 512, 512, 0, stream>>>(d_in[0], h, flag);

  if (big) {
    // layer 1
    k_gemmkvqs<<<GSB, 512, 0, stream>>>(h, PKV0, PQS0, Bk0, Bv0, Bq0, Bs0,
                                        Kt, Vt, Qt, St);
    k_edge64b<false><<<GSB, 512, 0, stream>>>(off, csr, h, Qt, St, Kt, Vt, h);
    // layer 2
    k_gemmkvqs<<<GSB, 512, 0, stream>>>(h, PKV1, PQS1, Bk1, Bv1, Bq1, Bs1,
                                        Kt, Vt, Qt, St);
    k_edge64b<true><<<GSB, 512, 0, stream>>>(off, csr, h, Qt, St, Kt, Vt, h);
  } else {
    const int gw = N_NODES / 4;
    // layer 1
    k_gemmkv<<<gw, 256, 0, stream>>>(h, PKV0, Bk0, Bv0, Kt, Vt);
    k_edge64<false><<<gw, 256, 0, stream>>>(off, csr, h, PQS0, Bq0, Bs0, Kt, Vt, h);
    // layer 2
    k_gemmkv<<<gw, 256, 0, stream>>>(h, PKV1, Bk1, Bv1, Kt, Vt);
    k_edge64<true><<<gw, 256, 0, stream>>>(off, csr, h, PQS1, Bq1, Bs1, Kt, Vt, h);
  }
  // layer 3
  k_gemm3<<<GSB, 512, 0, stream>>>(h, W3q, B3q, W3k, B3k, W3v, B3v, W3s, B3s,
                                   Q3, S3, KV3);
  k_edge3<<<GSB, 512, 0, stream>>>(off, csr, Q3, S3, KV3, d_in[2], d_out, flag);
}

// Round 9
// 783.220 us; speedup vs baseline: 1.1748x; 1.1748x over previous
//
#include <hip/hip_runtime.h>

#define N_NODES 100000
#define N_EDGES 3200000
// bucket partition: bucket = dst >> 8 (256 nodes per bucket)
#define NBUK 391   // ceil(N_NODES / 256)
#define NPB 256
#define CHUNK 8192
#define NCHUNK 391  // ceil(N_EDGES / CHUNK); 391*8192 = 3,203,072 >= 3.2M

#if defined(__has_builtin)
#if __has_builtin(__builtin_amdgcn_fdot2_f32_bf16)
#define HAS_DOT2 1
#endif
#endif
#ifndef HAS_DOT2
#define HAS_DOT2 0
#endif

__device__ __forceinline__ float bf2f(unsigned short u) {
  return __uint_as_float(((unsigned)u) << 16);
}
__device__ __forceinline__ unsigned short f2bf(float f) {
  unsigned u = __float_as_uint(f);
  u += 0x7fffu + ((u >> 16) & 1u);
  return (unsigned short)(u >> 16);
}
__device__ __forceinline__ float lo16(unsigned u) { return __uint_as_float(u << 16); }
__device__ __forceinline__ float hi16(unsigned u) { return __uint_as_float(u & 0xffff0000u); }

// ---------------- dtype detection (flag=1: bf16 storage, 0: fp32) ----------------

__global__ void k_detect(const unsigned short* __restrict__ xu, int* __restrict__ flag) {
  __shared__ int cnt;
  if (threadIdx.x == 0) cnt = 0;
  __syncthreads();
  int c = 0;
  for (int i = threadIdx.x; i < 4096; i += 256) {
    float v = fabsf(bf2f(xu[2 * i]));
    if (v >= 1e-4f && v <= 10.f) c++;
  }
  atomicAdd(&cnt, c);
  __syncthreads();
  if (threadIdx.x == 0) *flag = (cnt > 2048) ? 1 : 0;
}

// ---------------- canonicalize inputs to bf16 ----------------

__global__ __launch_bounds__(512) void k_cvt_x(const void* __restrict__ x,
                                               unsigned short* __restrict__ xb,
                                               const int* __restrict__ flag) {
  int i = blockIdx.x * 512 + threadIdx.x;  // one uint4 (8 bf16) per thread
  if (i >= N_NODES * 8) return;
  if (*flag) {
    ((uint4*)xb)[i] = ((const uint4*)x)[i];
  } else {
    const float4* xf = (const float4*)x;
    float4 a = xf[2 * i], b = xf[2 * i + 1];
    uint4 o;
    o.x = (unsigned)f2bf(a.x) | ((unsigned)f2bf(a.y) << 16);
    o.y = (unsigned)f2bf(a.z) | ((unsigned)f2bf(a.w) << 16);
    o.z = (unsigned)f2bf(b.x) | ((unsigned)f2bf(b.y) << 16);
    o.w = (unsigned)f2bf(b.z) | ((unsigned)f2bf(b.w) << 16);
    ((uint4*)xb)[i] = o;
  }
}

struct CvtArgs {
  const void* src[24];
  int dstoff[24];  // in shorts
  int n[24];
  int pp[24];      // 1 = pair-pack over k for [64][64] matrix (dot2 layout)
};

// pp layout: src index i -> k=i>>6, c=i&63; dst short = (k>>1)*128 + c*2 + (k&1)
// i.e. uint word kk*64+c holds W[2kk][c] | W[2kk+1][c]<<16.
__global__ void k_cvt_w(CvtArgs a, unsigned short* __restrict__ wb,
                        const int* __restrict__ flag) {
  int b = blockIdx.x;
  const void* s = a.src[b];
  int n = a.n[b];
  int pp = a.pp[b];
  unsigned short* d = wb + a.dstoff[b];
  int isbf = *flag;
  for (int i = threadIdx.x; i < n; i += 256) {
    unsigned short v = isbf ? ((const unsigned short*)s)[i] : f2bf(((const float*)s)[i]);
    if (pp) {
      int k = i >> 6, c = i & 63;
      d[((k >> 1) << 7) + (c << 1) + (k & 1)] = v;
    } else {
      d[i] = v;
    }
  }
}

// ---------------- CSR build: two-level bucket partition ----------------

// A1: per-chunk bucket histogram
__global__ __launch_bounds__(256) void k_bhist(const int* __restrict__ dsts,
                                               int* __restrict__ counts) {
  __shared__ int hist[NBUK];
  for (int i = threadIdx.x; i < NBUK; i += 256) hist[i] = 0;
  __syncthreads();
  int e0 = blockIdx.x * CHUNK;
  int n = min(CHUNK, N_EDGES - e0);
  for (int i = threadIdx.x; i < n; i += 256)
    atomicAdd(&hist[dsts[e0 + i] >> 8], 1);
  __syncthreads();
  for (int i = threadIdx.x; i < NBUK; i += 256)
    counts[blockIdx.x * NBUK + i] = hist[i];  // chunk-major
}

// A2a: per-bucket exclusive prefix over chunks (one wave per bucket) + total
__global__ __launch_bounds__(64) void k_bscanA(int* __restrict__ counts,
                                               int* __restrict__ tot) {
  int b = blockIdx.x;
  int lane = threadIdx.x;
  int carry = 0;
  for (int c0 = 0; c0 < NCHUNK; c0 += 64) {
    int c = c0 + lane;
    int v = (c < NCHUNK) ? counts[c * NBUK + b] : 0;
    int s = v;
#pragma unroll
    for (int o = 1; o < 64; o <<= 1) {
      int u = __shfl_up(s, o, 64);
      if (lane >= o) s += u;
    }
    if (c < NCHUNK) counts[c * NBUK + b] = s - v + carry;  // bucket-local base
    carry += __shfl(s, 63, 64);
  }
  if (lane == 0) tot[b] = carry;
}

// A2b: scan bucket totals -> bbase
__global__ void k_bscanB(const int* __restrict__ tot, int* __restrict__ bbase) {
  __shared__ int s[512];
  int t = threadIdx.x;
  int v = (t < NBUK) ? tot[t] : 0;
  s[t] = v;
  __syncthreads();
  for (int o = 1; o < 512; o <<= 1) {
    int u = (t >= o) ? s[t - o] : 0;
    __syncthreads();
    s[t] += u;
    __syncthreads();
  }
  if (t <= NBUK) bbase[t] = s[t] - v;  // v==0 for t==NBUK -> total
}

// A3: rank-scatter packed (src<<8 | dst&255); bbase add folded in
__global__ __launch_bounds__(256) void k_bscat(const int* __restrict__ srcs,
                                               const int* __restrict__ dsts,
                                               const int* __restrict__ counts,
                                               const int* __restrict__ bbase,
                                               unsigned* __restrict__ blist) {
  __shared__ int cnt[NBUK];
  for (int i = threadIdx.x; i < NBUK; i += 256)
    cnt[i] = counts[blockIdx.x * NBUK + i] + bbase[i];
  __syncthreads();
  int e0 = blockIdx.x * CHUNK;
  int n = min(CHUNK, N_EDGES - e0);
  for (int i = threadIdx.x; i < n; i += 256) {
    int s = srcs[e0 + i];
    int d = dsts[e0 + i];
    int p = atomicAdd(&cnt[d >> 8], 1);
    blist[p] = ((unsigned)s << 8) | (unsigned)(d & 255);
  }
}

// B: fused per-bucket degree + scan + offset write + csr fill.
__global__ __launch_bounds__(256) void k_bfinal(const unsigned* __restrict__ blist,
                                                const int* __restrict__ bbase,
                                                int* __restrict__ off,
                                                int* __restrict__ csr) {
  __shared__ int hcnt[NPB];
  __shared__ int sc[NPB];
  int t = threadIdx.x;
  int b = blockIdx.x;
  int s = bbase[b], e = bbase[b + 1];
  hcnt[t] = 0;
  __syncthreads();
  for (int i = s + t; i < e; i += 256)
    atomicAdd(&hcnt[blist[i] & 255], 1);
  __syncthreads();
  int v = hcnt[t];
  sc[t] = v;
  __syncthreads();
  for (int o = 1; o < 256; o <<= 1) {
    int u = (t >= o) ? sc[t - o] : 0;
    __syncthreads();
    sc[t] += u;
    __syncthreads();
  }
  int my = s + sc[t] - v;  // global csr offset of this node
  int node = b * NPB + t;
  if (node < N_NODES) off[node] = my;
  if (b == 0 && t == 0) off[N_NODES] = bbase[NBUK];
  sc[t] = my;  // becomes the scatter cursor
  __syncthreads();
  for (int i = s + t; i < e; i += 256) {
    unsigned u = blist[i];
    int p = atomicAdd(&sc[u & 255], 1);
    csr[p] = (int)(u >> 8);
  }
}

// ---------------- fused K,V,Q,S projection: dot2 pair-packed ----------------
// Wave per row (round-7 launch shape: 25000 blocks x 256, dynamic balancing).
// Pair-packed weights + packed h pairs: one v_dot2_f32_bf16 replaces
// {2 unpacks + 2 FMAs} -> VALU floor ~62us -> ~26us per call.

#if HAS_DOT2
typedef __bf16 bf16x2 __attribute__((ext_vector_type(2)));
__device__ __forceinline__ float dot2bf(unsigned h2, unsigned w2, float acc) {
  return __builtin_amdgcn_fdot2_f32_bf16(__builtin_bit_cast(bf16x2, h2),
                                         __builtin_bit_cast(bf16x2, w2), acc, false);
}
#else
__device__ __forceinline__ float dot2bf(unsigned h2, unsigned w2, float acc) {
  acc += lo16(h2) * lo16(w2);
  acc += hi16(h2) * hi16(w2);
  return acc;
}
#endif

__global__ __launch_bounds__(256) void k_gemmkvqs(
    const unsigned short* __restrict__ hin,
    const unsigned* __restrict__ PQ2, const unsigned* __restrict__ PK2,
    const unsigned* __restrict__ PV2, const unsigned* __restrict__ PS2,
    const unsigned short* __restrict__ bq, const unsigned short* __restrict__ bk,
    const unsigned short* __restrict__ bv, const unsigned short* __restrict__ bs,
    unsigned short* __restrict__ Kt, unsigned short* __restrict__ Vt,
    float* __restrict__ Qt, float* __restrict__ St) {
  int r = blockIdx.x * 4 + (threadIdx.x >> 6);
  int lane = threadIdx.x & 63;
  // lanes 0..31 hold the row's 32 bf16 pairs (lanes 32..63 duplicate)
  unsigned hp = ((const unsigned*)(hin + (size_t)r * 64))[lane & 31];
  float qa = bf2f(bq[lane]);
  float ka = bf2f(bk[lane]);
  float va = bf2f(bv[lane]);
  float sa = bf2f(bs[lane]);
  for (int kk = 0; kk < 32; ++kk) {
    unsigned hb = __shfl(hp, kk, 64);
    qa = dot2bf(hb, PQ2[kk * 64 + lane], qa);
    ka = dot2bf(hb, PK2[kk * 64 + lane], ka);
    va = dot2bf(hb, PV2[kk * 64 + lane], va);
    sa = dot2bf(hb, PS2[kk * 64 + lane], sa);
  }
  Kt[(size_t)r * 64 + lane] = f2bf(ka);
  Vt[(size_t)r * 64 + lane] = f2bf(va);
  Qt[(size_t)r * 64 + lane] = qa;
  St[(size_t)r * 64 + lane] = sa;
}

// ---------------- edge pass, C=64: round-7 exact body (best: 136us) ----------------
// 256-thread blocks, wave per dst, per-node grid (dynamic WG balancing).
// Do NOT grid-stride (r8: 199us) or add register pressure (r4: 289us) or
// min-waves bounds (r5: spill, 622us).

template <bool RES>
__global__ __launch_bounds__(256) void k_edge64b(
    const int* __restrict__ off, const int* __restrict__ csr,
    const unsigned short* __restrict__ hin,
    const float* __restrict__ Qt, const float* __restrict__ St,
    const unsigned short* __restrict__ Kt, const unsigned short* __restrict__ Vt,
    unsigned short* __restrict__ hout) {
  __shared__ float qs[4][64];
  int w = threadIdx.x >> 6;
  int lane = threadIdx.x & 63;
  int wid = blockIdx.x * 4 + w;
  int base = off[wid];
  int deg = off[wid + 1] - base;
  int nsrc = csr[base + ((lane < deg) ? lane : 0)];
  float q = Qt[(size_t)wid * 64 + lane];
  float sk = St[(size_t)wid * 64 + lane];
  float hv = 0.f;
  if (RES) hv = bf2f(hin[(size_t)wid * 64 + lane]);
  qs[w][lane] = q;  // wave-local write->read; lgkmcnt ordering within wave

  float m = -1e30f, ssum = 0.f;
  float4 acc = {0.f, 0.f, 0.f, 0.f};
  int g = lane >> 4;
  int c16 = lane & 15;
  const float4* qv = (const float4*)qs[w];

  for (int j0 = 0; j0 < deg; j0 += 64) {
    int cnt = min(64, deg - j0);
    int src = nsrc;
    int nj = j0 + 64;
    if (nj < deg)
      nsrc = csr[base + nj + ((lane < deg - nj) ? lane : 0)];
    const uint4* kp = (const uint4*)(Kt + (size_t)src * 64);
    float d0 = 0.f, d1 = 0.f, d2 = 0.f, d3 = 0.f;
#pragma unroll
    for (int i = 0; i < 8; ++i) {
      uint4 kk = kp[i];
      float4 qa = qv[2 * i];
      float4 qb = qv[2 * i + 1];
      d0 += qa.x * lo16(kk.x); d1 += qa.y * hi16(kk.x);
      d2 += qa.z * lo16(kk.y); d3 += qa.w * hi16(kk.y);
      d0 += qb.x * lo16(kk.z); d1 += qb.y * hi16(kk.z);
      d2 += qb.z * lo16(kk.w); d3 += qb.w * hi16(kk.w);
    }
    float sc = ((d0 + d1) + (d2 + d3)) * 0.125f;
    sc = fminf(fmaxf(sc, -60.f), 60.f);
    if (lane >= cnt) sc = -1e30f;
    float bm = sc;
    bm = fmaxf(bm, __shfl_xor(bm, 32, 64));
    bm = fmaxf(bm, __shfl_xor(bm, 16, 64));
    bm = fmaxf(bm, __shfl_xor(bm, 8, 64));
    bm = fmaxf(bm, __shfl_xor(bm, 4, 64));
    bm = fmaxf(bm, __shfl_xor(bm, 2, 64));
    bm = fmaxf(bm, __shfl_xor(bm, 1, 64));
    float mn = fmaxf(m, bm);
    float al = __expf(sc - mn);
    float bsum = al;
    bsum += __shfl_xor(bsum, 32, 64);
    bsum += __shfl_xor(bsum, 16, 64);
    bsum += __shfl_xor(bsum, 8, 64);
    bsum += __shfl_xor(bsum, 4, 64);
    bsum += __shfl_xor(bsum, 2, 64);
    bsum += __shfl_xor(bsum, 1, 64);
    float corr = __expf(m - mn);
    ssum = ssum * corr + bsum;
    acc.x *= corr;
    acc.y *= corr;
    acc.z *= corr;
    acc.w *= corr;
    m = mn;
    for (int jj = 0; jj < cnt; jj += 16) {
      int e0 = jj + g, e1 = jj + 4 + g, e2 = jj + 8 + g, e3 = jj + 12 + g;
      int s0 = __shfl(src, e0, 64);
      int s1 = __shfl(src, e1, 64);
      int s2 = __shfl(src, e2, 64);
      int s3 = __shfl(src, e3, 64);
      float a0 = __shfl(al, e0, 64);
      float a1 = __shfl(al, e1, 64);
      float a2 = __shfl(al, e2, 64);
      float a3 = __shfl(al, e3, 64);
      uint2 v0 = *(const uint2*)(Vt + (size_t)s0 * 64 + c16 * 4);
      uint2 v1 = *(const uint2*)(Vt + (size_t)s1 * 64 + c16 * 4);
      uint2 v2 = *(const uint2*)(Vt + (size_t)s2 * 64 + c16 * 4);
      uint2 v3 = *(const uint2*)(Vt + (size_t)s3 * 64 + c16 * 4);
      acc.x += a0 * lo16(v0.x); acc.y += a0 * hi16(v0.x);
      acc.z += a0 * lo16(v0.y); acc.w += a0 * hi16(v0.y);
      acc.x += a1 * lo16(v1.x); acc.y += a1 * hi16(v1.x);
      acc.z += a1 * lo16(v1.y); acc.w += a1 * hi16(v1.y);
      acc.x += a2 * lo16(v2.x); acc.y += a2 * hi16(v2.x);
      acc.z += a2 * lo16(v2.y); acc.w += a2 * hi16(v2.y);
      acc.x += a3 * lo16(v3.x); acc.y += a3 * hi16(v3.x);
      acc.z += a3 * lo16(v3.y); acc.w += a3 * hi16(v3.y);
    }
  }
  acc.x += __shfl_xor(acc.x, 16, 64);
  acc.y += __shfl_xor(acc.y, 16, 64);
  acc.z += __shfl_xor(acc.z, 16, 64);
  acc.w += __shfl_xor(acc.w, 16, 64);
  acc.x += __shfl_xor(acc.x, 32, 64);
  acc.y += __shfl_xor(acc.y, 32, 64);
  acc.z += __shfl_xor(acc.z, 32, 64);
  acc.w += __shfl_xor(acc.w, 32, 64);
  float f0 = __shfl(acc.x, lane >> 2, 64);
  float f1 = __shfl(acc.y, lane >> 2, 64);
  float f2 = __shfl(acc.z, lane >> 2, 64);
  float f3 = __shfl(acc.w, lane >> 2, 64);
  int cc = lane & 3;
  float aggv = (cc == 0) ? f0 : ((cc == 1) ? f1 : ((cc == 2) ? f2 : f3));
  float val = aggv / (ssum + 1e-16f) + sk;
  if (RES) val += hv;
  hout[(size_t)wid * 64 + lane] = f2bf(tanhf(val));
}

// ---------------- layer 3 projections (C=3): wave per node (round-7) ----------------

__global__ __launch_bounds__(256) void k_gemm3(
    const unsigned short* __restrict__ hin,
    const unsigned short* __restrict__ Wq, const unsigned short* __restrict__ bq,
    const unsigned short* __restrict__ Wk, const unsigned short* __restrict__ bk,
    const unsigned short* __restrict__ Wv, const unsigned short* __restrict__ bv,
    const unsigned short* __restrict__ Ws, const unsigned short* __restrict__ bs,
    float* __restrict__ Q3, float* __restrict__ S3, uint4* __restrict__ KV3) {
  int r = blockIdx.x * 4 + (threadIdx.x >> 6);
  int lane = threadIdx.x & 63;
  float hj = bf2f(hin[(size_t)r * 64 + lane]);
  float p[12];
#pragma unroll
  for (int c = 0; c < 3; ++c) {
    p[c]     = hj * bf2f(Wq[lane * 3 + c]);
    p[3 + c] = hj * bf2f(Wk[lane * 3 + c]);
    p[6 + c] = hj * bf2f(Wv[lane * 3 + c]);
    p[9 + c] = hj * bf2f(Ws[lane * 3 + c]);
  }
#pragma unroll
  for (int o = 32; o >= 1; o >>= 1) {
#pragma unroll
    for (int i = 0; i < 12; ++i) p[i] += __shfl_xor(p[i], o, 64);
  }
  if (lane == 0) {
    float kk[3], vv[3];
    for (int c = 0; c < 3; ++c) {
      Q3[r * 4 + c] = p[c] + bf2f(bq[c]);
      S3[r * 4 + c] = p[9 + c] + bf2f(bs[c]);
      kk[c] = p[3 + c] + bf2f(bk[c]);
      vv[c] = p[6 + c] + bf2f(bv[c]);
    }
    uint4 pk;
    pk.x = (unsigned)f2bf(kk[0]) | ((unsigned)f2bf(vv[0]) << 16);
    pk.y = (unsigned)f2bf(kk[1]) | ((unsigned)f2bf(vv[1]) << 16);
    pk.z = (unsigned)f2bf(kk[2]) | ((unsigned)f2bf(vv[2]) << 16);
    pk.w = 0;
    KV3[r] = pk;
  }
}

// ---------------- edge pass, C=3: wave per dst (round-7) ----------------

__global__ __launch_bounds__(256) void k_edge3(
    const int* __restrict__ off, const int* __restrict__ csr,
    const float* __restrict__ Q3, const float* __restrict__ S3,
    const uint4* __restrict__ KV3, const void* __restrict__ noise,
    void* __restrict__ out, const int* __restrict__ flag) {
  int w = threadIdx.x >> 6;
  int lane = threadIdx.x & 63;
  int d = blockIdx.x * 4 + w;
  int base = off[d];
  int deg = off[d + 1] - base;
  float q0 = Q3[d * 4], q1 = Q3[d * 4 + 1], q2 = Q3[d * 4 + 2];
  const float isq = 0.57735026919f;  // 1/sqrt(3)
  float m = -1e30f, ssum = 0.f, a0 = 0.f, a1 = 0.f, a2 = 0.f;
  for (int j0 = 0; j0 < deg; j0 += 64) {
    int cnt = min(64, deg - j0);
    int src = csr[base + ((lane < cnt) ? (j0 + lane) : 0)];
    uint4 kv = KV3[src];
    float sc = (q0 * lo16(kv.x) + q1 * lo16(kv.y) + q2 * lo16(kv.z)) * isq;
    sc = fminf(fmaxf(sc, -60.f), 60.f);
    if (lane >= cnt) sc = -1e30f;
    float bm = sc;
#pragma unroll
    for (int o = 32; o >= 1; o >>= 1) bm = fmaxf(bm, __shfl_xor(bm, o, 64));
    float mn = fmaxf(m, bm);
    float al = __expf(sc - mn);  // inactive lanes -> 0
    float p0 = al * hi16(kv.x);
    float p1 = al * hi16(kv.y);
    float p2 = al * hi16(kv.z);
    float bsum = al;
#pragma unroll
    for (int o = 32; o >= 1; o >>= 1) {
      bsum += __shfl_xor(bsum, o, 64);
      p0 += __shfl_xor(p0, o, 64);
      p1 += __shfl_xor(p1, o, 64);
      p2 += __shfl_xor(p2, o, 64);
    }
    float corr = __expf(m - mn);
    ssum = ssum * corr + bsum;
    a0 = a0 * corr + p0;
    a1 = a1 * corr + p1;
    a2 = a2 * corr + p2;
    m = mn;
  }
  if (lane == 0) {
    float inv = 1.f / (ssum + 1e-16f);
    int isbf = *flag;
    float n0, n1, n2;
    if (isbf) {
      const unsigned short* nu = (const unsigned short*)noise;
      n0 = bf2f(nu[d * 3 + 0]);
      n1 = bf2f(nu[d * 3 + 1]);
      n2 = bf2f(nu[d * 3 + 2]);
    } else {
      const float* nf = (const float*)noise;
      n0 = nf[d * 3 + 0];
      n1 = nf[d * 3 + 1];
      n2 = nf[d * 3 + 2];
    }
    float r0 = a0 * inv + S3[d * 4 + 0] + 0.1f * n0;
    float r1 = a1 * inv + S3[d * 4 + 1] + 0.1f * n1;
    float r2 = a2 * inv + S3[d * 4 + 2] + 0.1f * n2;
    if (isbf) {
      unsigned short* ou = (unsigned short*)out;
      ou[d * 3 + 0] = f2bf(r0);
      ou[d * 3 + 1] = f2bf(r1);
      ou[d * 3 + 2] = f2bf(r2);
    } else {
      float* of = (float*)out;
      of[d * 3 + 0] = r0;
      of[d * 3 + 1] = r1;
      of[d * 3 + 2] = r2;
    }
  }
}

// ---------------- launch ----------------

extern "C" void kernel_launch(void* const* d_in, const int* in_sizes, int n_in,
                              void* d_out, int out_size, void* d_ws, size_t ws_size,
                              hipStream_t stream) {
  const int* ei = (const int*)d_in[1];
  const int* srcs = ei;
  const int* dsts = ei + N_EDGES;

  // Workspace layout (NEED_BIG = 102868480 B, proven available in rounds 7-8):
  //   off @0 | csr @400128 | h @13200128 (bf16; CSR-build scratch aliased)
  //   kvbase @26000128: blist during build; then Kt/Vt bf16; Q3/S3/KV3 layer 3
  //   wb @51600128 | flag @51668352 | Qt f32 @51668480 | St f32 @77268480
  char* w = (char*)d_ws;
  int* off = (int*)w;
  int* csr = (int*)(w + 400128);
  char* hreg = w + 13200128;
  unsigned short* h = (unsigned short*)hreg;
  int* counts = (int*)(hreg + 524288);   // NCHUNK*NBUK ints = 611,524 B
  int* bbase = (int*)(hreg + 1200128);   // NBUK+1 ints
  int* tot = (int*)(hreg + 1310720);     // NBUK ints
  char* kvbase = w + 26000128;
  unsigned* blist = (unsigned*)kvbase;
  unsigned short* Kt = (unsigned short*)kvbase;
  unsigned short* Vt = (unsigned short*)(kvbase + 12800000);
  float* Q3 = (float*)kvbase;
  float* S3 = (float*)(kvbase + 2097152);
  uint4* KV3 = (uint4*)(kvbase + 4194304);
  unsigned short* wb = (unsigned short*)(w + 51600128);
  int* flag = (int*)(w + 51668352);
  float* Qt = (float*)(w + 51668480);
  float* St = (float*)(w + 77268480);
  const size_t NEED_BIG = 102868480;
  if (ws_size < NEED_BIG) return;

  // wb layout (shorts), per layer l in {0,1} at l*16640:
  //   PQ2 @+0, PK2 @+4096, PV2 @+8192, PS2 @+12288 (pair-packed over k)
  //   bq @+16384, bk @+16448, bv @+16512, bs @+16576
  // layer 3 @33280: Wq(192) bq(3) Wk bk Wv bv Ws bs, linear.
  CvtArgs ca;
  {
    int idx = 0;
    for (int l = 0; l < 2; ++l) {
      int base = l * 16640;
      for (int p = 0; p < 4; ++p) {  // p: 0=q,1=k,2=v,3=s
        ca.src[idx] = d_in[3 + l * 8 + p * 2];
        ca.dstoff[idx] = base + p * 4096;
        ca.n[idx] = 4096;
        ca.pp[idx] = 1;
        idx++;
        ca.src[idx] = d_in[3 + l * 8 + p * 2 + 1];
        ca.dstoff[idx] = base + 16384 + p * 64;
        ca.n[idx] = 64;
        ca.pp[idx] = 0;
        idx++;
      }
    }
    int o = 33280;  // layer 3, linear
    for (int p = 0; p < 4; ++p) {
      ca.src[idx] = d_in[3 + 16 + p * 2];
      ca.dstoff[idx] = o;
      ca.n[idx] = 192;
      ca.pp[idx] = 0;
      o += 192;
      idx++;
      ca.src[idx] = d_in[3 + 16 + p * 2 + 1];
      ca.dstoff[idx] = o;
      ca.n[idx] = 3;
      ca.pp[idx] = 0;
      o += 3;
      idx++;
    }
  }
  const unsigned* PQ20 = (const unsigned*)(wb);
  const unsigned* PK20 = (const unsigned*)(wb + 4096);
  const unsigned* PV20 = (const unsigned*)(wb + 8192);
  const unsigned* PS20 = (const unsigned*)(wb + 12288);
  const unsigned* PQ21 = (const unsigned*)(wb + 16640);
  const unsigned* PK21 = (const unsigned*)(wb + 16640 + 4096);
  const unsigned* PV21 = (const unsigned*)(wb + 16640 + 8192);
  const unsigned* PS21 = (const unsigned*)(wb + 16640 + 12288);
  const unsigned short* Bq0 = wb + 16384;
  const unsigned short* Bk0 = wb + 16448;
  const unsigned short* Bv0 = wb + 16512;
  const unsigned short* Bs0 = wb + 16576;
  const unsigned short* Bq1 = wb + 16640 + 16384;
  const unsigned short* Bk1 = wb + 16640 + 16448;
  const unsigned short* Bv1 = wb + 16640 + 16512;
  const unsigned short* Bs1 = wb + 16640 + 16576;
  const unsigned short* W3q = wb + 33280;
  const unsigned short* B3q = wb + 33472;
  const unsigned short* W3k = wb + 33475;
  const unsigned short* B3k = wb + 33667;
  const unsigned short* W3v = wb + 33670;
  const unsigned short* B3v = wb + 33862;
  const unsigned short* W3s = wb + 33865;
  const unsigned short* B3s = wb + 34057;

  k_detect<<<1, 256, 0, stream>>>((const unsigned short*)d_in[0], flag);
  k_cvt_w<<<24, 256, 0, stream>>>(ca, wb, flag);

  // CSR build (uses hreg + kvbase as scratch; must precede k_cvt_x)
  k_bhist<<<NCHUNK, 256, 0, stream>>>(dsts, counts);
  k_bscanA<<<NBUK, 64, 0, stream>>>(counts, tot);
  k_bscanB<<<1, 512, 0, stream>>>(tot, bbase);
  k_bscat<<<NCHUNK, 256, 0, stream>>>(srcs, dsts, counts, bbase, blist);
  k_bfinal<<<NBUK, 256, 0, stream>>>(blist, bbase, off, csr);

  k_cvt_x<<<(N_NODES * 8 + 511) / 512, 512, 0, stream>>>(d_in[0], h, flag);

  const int gw = N_NODES / 4;  // 25000 blocks x 4 waves (dynamic balancing)
  // layer 1
  k_gemmkvqs<<<gw, 256, 0, stream>>>(h, PQ20, PK20, PV20, PS20,
                                     Bq0, Bk0, Bv0, Bs0, Kt, Vt, Qt, St);
  k_edge64b<false><<<gw, 256, 0, stream>>>(off, csr, h, Qt, St, Kt, Vt, h);
  // layer 2
  k_gemmkvqs<<<gw, 256, 0, stream>>>(h, PQ21, PK21, PV21, PS21,
                                     Bq1, Bk1, Bv1, Bs1, Kt, Vt, Qt, St);
  k_edge64b<true><<<gw, 256, 0, stream>>>(off, csr, h, Qt, St, Kt, Vt, h);
  // layer 3
  k_gemm3<<<gw, 256, 0, stream>>>(h, W3q, B3q, W3k, B3k, W3v, B3v, W3s, B3s,
                                  Q3, S3, KV3);
  k_edge3<<<gw, 256, 0, stream>>>(off, csr, Q3, S3, KV3, d_in[2], d_out, flag);
}

// Round 10
// 674.155 us; speedup vs baseline: 1.3648x; 1.1618x over previous
//
#include <hip/hip_runtime.h>

#define N_NODES 100000
#define N_EDGES 3200000
// bucket partition: bucket = dst >> 8 (256 nodes per bucket)
#define NBUK 391   // ceil(N_NODES / 256)
#define NPB 256
#define CHUNK 8192
#define NCHUNK 391  // ceil(N_EDGES / CHUNK); 391*8192 = 3,203,072 >= 3.2M

#if defined(__has_builtin)
#if __has_builtin(__builtin_amdgcn_fdot2_f32_bf16)
#define HAS_DOT2 1
#endif
#endif
#ifndef HAS_DOT2
#define HAS_DOT2 0
#endif

__device__ __forceinline__ float bf2f(unsigned short u) {
  return __uint_as_float(((unsigned)u) << 16);
}
__device__ __forceinline__ unsigned short f2bf(float f) {
  unsigned u = __float_as_uint(f);
  u += 0x7fffu + ((u >> 16) & 1u);
  return (unsigned short)(u >> 16);
}
__device__ __forceinline__ float lo16(unsigned u) { return __uint_as_float(u << 16); }
__device__ __forceinline__ float hi16(unsigned u) { return __uint_as_float(u & 0xffff0000u); }

// ---------------- dtype detection (flag=1: bf16 storage, 0: fp32) ----------------

__global__ void k_detect(const unsigned short* __restrict__ xu, int* __restrict__ flag) {
  __shared__ int cnt;
  if (threadIdx.x == 0) cnt = 0;
  __syncthreads();
  int c = 0;
  for (int i = threadIdx.x; i < 4096; i += 256) {
    float v = fabsf(bf2f(xu[2 * i]));
    if (v >= 1e-4f && v <= 10.f) c++;
  }
  atomicAdd(&cnt, c);
  __syncthreads();
  if (threadIdx.x == 0) *flag = (cnt > 2048) ? 1 : 0;
}

// ---------------- canonicalize inputs to bf16 ----------------

__global__ __launch_bounds__(512) void k_cvt_x(const void* __restrict__ x,
                                               unsigned short* __restrict__ xb,
                                               const int* __restrict__ flag) {
  int i = blockIdx.x * 512 + threadIdx.x;  // one uint4 (8 bf16) per thread
  if (i >= N_NODES * 8) return;
  if (*flag) {
    ((uint4*)xb)[i] = ((const uint4*)x)[i];
  } else {
    const float4* xf = (const float4*)x;
    float4 a = xf[2 * i], b = xf[2 * i + 1];
    uint4 o;
    o.x = (unsigned)f2bf(a.x) | ((unsigned)f2bf(a.y) << 16);
    o.y = (unsigned)f2bf(a.z) | ((unsigned)f2bf(a.w) << 16);
    o.z = (unsigned)f2bf(b.x) | ((unsigned)f2bf(b.y) << 16);
    o.w = (unsigned)f2bf(b.z) | ((unsigned)f2bf(b.w) << 16);
    ((uint4*)xb)[i] = o;
  }
}

struct CvtArgs {
  const void* src[24];
  int dstoff[24];  // in shorts
  int n[24];
  int pp[24];      // 1 = pair-pack over k for [64][64] matrix (dot2 layout)
};

// pp layout: src index i -> k=i>>6, c=i&63; dst short = (k>>1)*128 + c*2 + (k&1)
// i.e. uint word kk*64+c holds W[2kk][c] | W[2kk+1][c]<<16.
__global__ void k_cvt_w(CvtArgs a, unsigned short* __restrict__ wb,
                        const int* __restrict__ flag) {
  int b = blockIdx.x;
  const void* s = a.src[b];
  int n = a.n[b];
  int pp = a.pp[b];
  unsigned short* d = wb + a.dstoff[b];
  int isbf = *flag;
  for (int i = threadIdx.x; i < n; i += 256) {
    unsigned short v = isbf ? ((const unsigned short*)s)[i] : f2bf(((const float*)s)[i]);
    if (pp) {
      int k = i >> 6, c = i & 63;
      d[((k >> 1) << 7) + (c << 1) + (k & 1)] = v;
    } else {
      d[i] = v;
    }
  }
}

// ---------------- CSR build: two-level bucket partition ----------------

// A1: per-chunk bucket histogram
__global__ __launch_bounds__(256) void k_bhist(const int* __restrict__ dsts,
                                               int* __restrict__ counts) {
  __shared__ int hist[NBUK];
  for (int i = threadIdx.x; i < NBUK; i += 256) hist[i] = 0;
  __syncthreads();
  int e0 = blockIdx.x * CHUNK;
  int n = min(CHUNK, N_EDGES - e0);
  for (int i = threadIdx.x; i < n; i += 256)
    atomicAdd(&hist[dsts[e0 + i] >> 8], 1);
  __syncthreads();
  for (int i = threadIdx.x; i < NBUK; i += 256)
    counts[blockIdx.x * NBUK + i] = hist[i];  // chunk-major
}

// A2a: per-bucket exclusive prefix over chunks (one wave per bucket) + total
__global__ __launch_bounds__(64) void k_bscanA(int* __restrict__ counts,
                                               int* __restrict__ tot) {
  int b = blockIdx.x;
  int lane = threadIdx.x;
  int carry = 0;
  for (int c0 = 0; c0 < NCHUNK; c0 += 64) {
    int c = c0 + lane;
    int v = (c < NCHUNK) ? counts[c * NBUK + b] : 0;
    int s = v;
#pragma unroll
    for (int o = 1; o < 64; o <<= 1) {
      int u = __shfl_up(s, o, 64);
      if (lane >= o) s += u;
    }
    if (c < NCHUNK) counts[c * NBUK + b] = s - v + carry;  // bucket-local base
    carry += __shfl(s, 63, 64);
  }
  if (lane == 0) tot[b] = carry;
}

// A2b: scan bucket totals -> bbase
__global__ void k_bscanB(const int* __restrict__ tot, int* __restrict__ bbase) {
  __shared__ int s[512];
  int t = threadIdx.x;
  int v = (t < NBUK) ? tot[t] : 0;
  s[t] = v;
  __syncthreads();
  for (int o = 1; o < 512; o <<= 1) {
    int u = (t >= o) ? s[t - o] : 0;
    __syncthreads();
    s[t] += u;
    __syncthreads();
  }
  if (t <= NBUK) bbase[t] = s[t] - v;  // v==0 for t==NBUK -> total
}

// A3: rank-scatter packed (src<<8 | dst&255); bbase add folded in
__global__ __launch_bounds__(256) void k_bscat(const int* __restrict__ srcs,
                                               const int* __restrict__ dsts,
                                               const int* __restrict__ counts,
                                               const int* __restrict__ bbase,
                                               unsigned* __restrict__ blist) {
  __shared__ int cnt[NBUK];
  for (int i = threadIdx.x; i < NBUK; i += 256)
    cnt[i] = counts[blockIdx.x * NBUK + i] + bbase[i];
  __syncthreads();
  int e0 = blockIdx.x * CHUNK;
  int n = min(CHUNK, N_EDGES - e0);
  for (int i = threadIdx.x; i < n; i += 256) {
    int s = srcs[e0 + i];
    int d = dsts[e0 + i];
    int p = atomicAdd(&cnt[d >> 8], 1);
    blist[p] = ((unsigned)s << 8) | (unsigned)(d & 255);
  }
}

// B: fused per-bucket degree + scan + offset write + csr fill.
__global__ __launch_bounds__(256) void k_bfinal(const unsigned* __restrict__ blist,
                                                const int* __restrict__ bbase,
                                                int* __restrict__ off,
                                                int* __restrict__ csr) {
  __shared__ int hcnt[NPB];
  __shared__ int sc[NPB];
  int t = threadIdx.x;
  int b = blockIdx.x;
  int s = bbase[b], e = bbase[b + 1];
  hcnt[t] = 0;
  __syncthreads();
  for (int i = s + t; i < e; i += 256)
    atomicAdd(&hcnt[blist[i] & 255], 1);
  __syncthreads();
  int v = hcnt[t];
  sc[t] = v;
  __syncthreads();
  for (int o = 1; o < 256; o <<= 1) {
    int u = (t >= o) ? sc[t - o] : 0;
    __syncthreads();
    sc[t] += u;
    __syncthreads();
  }
  int my = s + sc[t] - v;  // global csr offset of this node
  int node = b * NPB + t;
  if (node < N_NODES) off[node] = my;
  if (b == 0 && t == 0) off[N_NODES] = bbase[NBUK];
  sc[t] = my;  // becomes the scatter cursor
  __syncthreads();
  for (int i = s + t; i < e; i += 256) {
    unsigned u = blist[i];
    int p = atomicAdd(&sc[u & 255], 1);
    csr[p] = (int)(u >> 8);
  }
}

// ---------------- fused K,V,Q,S projection: dot2 pair-packed, R=4 rows/wave ----
// Round-9 taught: the 1-row/wave version was L2-BANDWIDTH-bound on broadcast
// weight reads (100K waves x 32.8KB = 3.3GB -> ~95us at the 34.5 TB/s L2
// ceiling; dot2-vs-FMA was a ~null, confirming non-VALU-bound). Each wave now
// processes 4 consecutive rows so each table load feeds 4 dot2s: table
// traffic /4 (0.82GB ~ 24us), VALU ~25us. Per-row accumulation order is
// bit-identical to round 9.

#if HAS_DOT2
typedef __bf16 bf16x2 __attribute__((ext_vector_type(2)));
__device__ __forceinline__ float dot2bf(unsigned h2, unsigned w2, float acc) {
  return __builtin_amdgcn_fdot2_f32_bf16(__builtin_bit_cast(bf16x2, h2),
                                         __builtin_bit_cast(bf16x2, w2), acc, false);
}
#else
__device__ __forceinline__ float dot2bf(unsigned h2, unsigned w2, float acc) {
  acc += lo16(h2) * lo16(w2);
  acc += hi16(h2) * hi16(w2);
  return acc;
}
#endif

__global__ __launch_bounds__(256) void k_gemmkvqs(
    const unsigned short* __restrict__ hin,
    const unsigned* __restrict__ PQ2, const unsigned* __restrict__ PK2,
    const unsigned* __restrict__ PV2, const unsigned* __restrict__ PS2,
    const unsigned short* __restrict__ bq, const unsigned short* __restrict__ bk,
    const unsigned short* __restrict__ bv, const unsigned short* __restrict__ bs,
    unsigned short* __restrict__ Kt, unsigned short* __restrict__ Vt,
    float* __restrict__ Qt, float* __restrict__ St) {
  int wid = blockIdx.x * 4 + (threadIdx.x >> 6);  // 25000 waves
  int lane = threadIdx.x & 63;
  int r0 = wid * 4;  // 4 consecutive rows per wave
  // lanes 0..31 hold each row's 32 bf16 pairs (lanes 32..63 duplicate)
  const unsigned* hrow = (const unsigned*)(hin + (size_t)r0 * 64);
  unsigned hp0 = hrow[lane & 31];
  unsigned hp1 = hrow[32 + (lane & 31)];
  unsigned hp2 = hrow[64 + (lane & 31)];
  unsigned hp3 = hrow[96 + (lane & 31)];
  float bqv = bf2f(bq[lane]), bkv = bf2f(bk[lane]);
  float bvv = bf2f(bv[lane]), bsv = bf2f(bs[lane]);
  float qa0 = bqv, qa1 = bqv, qa2 = bqv, qa3 = bqv;
  float ka0 = bkv, ka1 = bkv, ka2 = bkv, ka3 = bkv;
  float va0 = bvv, va1 = bvv, va2 = bvv, va3 = bvv;
  float sa0 = bsv, sa1 = bsv, sa2 = bsv, sa3 = bsv;
  for (int kk = 0; kk < 32; ++kk) {
    unsigned wq = PQ2[kk * 64 + lane];
    unsigned wk = PK2[kk * 64 + lane];
    unsigned wv = PV2[kk * 64 + lane];
    unsigned ws = PS2[kk * 64 + lane];
    unsigned hb0 = __shfl(hp0, kk, 64);
    unsigned hb1 = __shfl(hp1, kk, 64);
    unsigned hb2 = __shfl(hp2, kk, 64);
    unsigned hb3 = __shfl(hp3, kk, 64);
    qa0 = dot2bf(hb0, wq, qa0); ka0 = dot2bf(hb0, wk, ka0);
    va0 = dot2bf(hb0, wv, va0); sa0 = dot2bf(hb0, ws, sa0);
    qa1 = dot2bf(hb1, wq, qa1); ka1 = dot2bf(hb1, wk, ka1);
    va1 = dot2bf(hb1, wv, va1); sa1 = dot2bf(hb1, ws, sa1);
    qa2 = dot2bf(hb2, wq, qa2); ka2 = dot2bf(hb2, wk, ka2);
    va2 = dot2bf(hb2, wv, va2); sa2 = dot2bf(hb2, ws, sa2);
    qa3 = dot2bf(hb3, wq, qa3); ka3 = dot2bf(hb3, wk, ka3);
    va3 = dot2bf(hb3, wv, va3); sa3 = dot2bf(hb3, ws, sa3);
  }
  Kt[(size_t)(r0 + 0) * 64 + lane] = f2bf(ka0);
  Kt[(size_t)(r0 + 1) * 64 + lane] = f2bf(ka1);
  Kt[(size_t)(r0 + 2) * 64 + lane] = f2bf(ka2);
  Kt[(size_t)(r0 + 3) * 64 + lane] = f2bf(ka3);
  Vt[(size_t)(r0 + 0) * 64 + lane] = f2bf(va0);
  Vt[(size_t)(r0 + 1) * 64 + lane] = f2bf(va1);
  Vt[(size_t)(r0 + 2) * 64 + lane] = f2bf(va2);
  Vt[(size_t)(r0 + 3) * 64 + lane] = f2bf(va3);
  Qt[(size_t)(r0 + 0) * 64 + lane] = qa0;
  Qt[(size_t)(r0 + 1) * 64 + lane] = qa1;
  Qt[(size_t)(r0 + 2) * 64 + lane] = qa2;
  Qt[(size_t)(r0 + 3) * 64 + lane] = qa3;
  St[(size_t)(r0 + 0) * 64 + lane] = sa0;
  St[(size_t)(r0 + 1) * 64 + lane] = sa1;
  St[(size_t)(r0 + 2) * 64 + lane] = sa2;
  St[(size_t)(r0 + 3) * 64 + lane] = sa3;
}

// ---------------- edge pass, C=64: round-7 exact body (best: 136us) ----------------
// 256-thread blocks, wave per dst, per-node grid (dynamic WG balancing).
// Do NOT grid-stride (r8: 199us) or add register pressure (r4: 289us) or
// min-waves bounds (r5: spill, 622us).

template <bool RES>
__global__ __launch_bounds__(256) void k_edge64b(
    const int* __restrict__ off, const int* __restrict__ csr,
    const unsigned short* __restrict__ hin,
    const float* __restrict__ Qt, const float* __restrict__ St,
    const unsigned short* __restrict__ Kt, const unsigned short* __restrict__ Vt,
    unsigned short* __restrict__ hout) {
  __shared__ float qs[4][64];
  int w = threadIdx.x >> 6;
  int lane = threadIdx.x & 63;
  int wid = blockIdx.x * 4 + w;
  int base = off[wid];
  int deg = off[wid + 1] - base;
  int nsrc = csr[base + ((lane < deg) ? lane : 0)];
  float q = Qt[(size_t)wid * 64 + lane];
  float sk = St[(size_t)wid * 64 + lane];
  float hv = 0.f;
  if (RES) hv = bf2f(hin[(size_t)wid * 64 + lane]);
  qs[w][lane] = q;  // wave-local write->read; lgkmcnt ordering within wave

  float m = -1e30f, ssum = 0.f;
  float4 acc = {0.f, 0.f, 0.f, 0.f};
  int g = lane >> 4;
  int c16 = lane & 15;
  const float4* qv = (const float4*)qs[w];

  for (int j0 = 0; j0 < deg; j0 += 64) {
    int cnt = min(64, deg - j0);
    int src = nsrc;
    int nj = j0 + 64;
    if (nj < deg)
      nsrc = csr[base + nj + ((lane < deg - nj) ? lane : 0)];
    const uint4* kp = (const uint4*)(Kt + (size_t)src * 64);
    float d0 = 0.f, d1 = 0.f, d2 = 0.f, d3 = 0.f;
#pragma unroll
    for (int i = 0; i < 8; ++i) {
      uint4 kk = kp[i];
      float4 qa = qv[2 * i];
      float4 qb = qv[2 * i + 1];
      d0 += qa.x * lo16(kk.x); d1 += qa.y * hi16(kk.x);
      d2 += qa.z * lo16(kk.y); d3 += qa.w * hi16(kk.y);
      d0 += qb.x * lo16(kk.z); d1 += qb.y * hi16(kk.z);
      d2 += qb.z * lo16(kk.w); d3 += qb.w * hi16(kk.w);
    }
    float sc = ((d0 + d1) + (d2 + d3)) * 0.125f;
    sc = fminf(fmaxf(sc, -60.f), 60.f);
    if (lane >= cnt) sc = -1e30f;
    float bm = sc;
    bm = fmaxf(bm, __shfl_xor(bm, 32, 64));
    bm = fmaxf(bm, __shfl_xor(bm, 16, 64));
    bm = fmaxf(bm, __shfl_xor(bm, 8, 64));
    bm = fmaxf(bm, __shfl_xor(bm, 4, 64));
    bm = fmaxf(bm, __shfl_xor(bm, 2, 64));
    bm = fmaxf(bm, __shfl_xor(bm, 1, 64));
    float mn = fmaxf(m, bm);
    float al = __expf(sc - mn);
    float bsum = al;
    bsum += __shfl_xor(bsum, 32, 64);
    bsum += __shfl_xor(bsum, 16, 64);
    bsum += __shfl_xor(bsum, 8, 64);
    bsum += __shfl_xor(bsum, 4, 64);
    bsum += __shfl_xor(bsum, 2, 64);
    bsum += __shfl_xor(bsum, 1, 64);
    float corr = __expf(m - mn);
    ssum = ssum * corr + bsum;
    acc.x *= corr;
    acc.y *= corr;
    acc.z *= corr;
    acc.w *= corr;
    m = mn;
    for (int jj = 0; jj < cnt; jj += 16) {
      int e0 = jj + g, e1 = jj + 4 + g, e2 = jj + 8 + g, e3 = jj + 12 + g;
      int s0 = __shfl(src, e0, 64);
      int s1 = __shfl(src, e1, 64);
      int s2 = __shfl(src, e2, 64);
      int s3 = __shfl(src, e3, 64);
      float a0 = __shfl(al, e0, 64);
      float a1 = __shfl(al, e1, 64);
      float a2 = __shfl(al, e2, 64);
      float a3 = __shfl(al, e3, 64);
      uint2 v0 = *(const uint2*)(Vt + (size_t)s0 * 64 + c16 * 4);
      uint2 v1 = *(const uint2*)(Vt + (size_t)s1 * 64 + c16 * 4);
      uint2 v2 = *(const uint2*)(Vt + (size_t)s2 * 64 + c16 * 4);
      uint2 v3 = *(const uint2*)(Vt + (size_t)s3 * 64 + c16 * 4);
      acc.x += a0 * lo16(v0.x); acc.y += a0 * hi16(v0.x);
      acc.z += a0 * lo16(v0.y); acc.w += a0 * hi16(v0.y);
      acc.x += a1 * lo16(v1.x); acc.y += a1 * hi16(v1.x);
      acc.z += a1 * lo16(v1.y); acc.w += a1 * hi16(v1.y);
      acc.x += a2 * lo16(v2.x); acc.y += a2 * hi16(v2.x);
      acc.z += a2 * lo16(v2.y); acc.w += a2 * hi16(v2.y);
      acc.x += a3 * lo16(v3.x); acc.y += a3 * hi16(v3.x);
      acc.z += a3 * lo16(v3.y); acc.w += a3 * hi16(v3.y);
    }
  }
  acc.x += __shfl_xor(acc.x, 16, 64);
  acc.y += __shfl_xor(acc.y, 16, 64);
  acc.z += __shfl_xor(acc.z, 16, 64);
  acc.w += __shfl_xor(acc.w, 16, 64);
  acc.x += __shfl_xor(acc.x, 32, 64);
  acc.y += __shfl_xor(acc.y, 32, 64);
  acc.z += __shfl_xor(acc.z, 32, 64);
  acc.w += __shfl_xor(acc.w, 32, 64);
  float f0 = __shfl(acc.x, lane >> 2, 64);
  float f1 = __shfl(acc.y, lane >> 2, 64);
  float f2 = __shfl(acc.z, lane >> 2, 64);
  float f3 = __shfl(acc.w, lane >> 2, 64);
  int cc = lane & 3;
  float aggv = (cc == 0) ? f0 : ((cc == 1) ? f1 : ((cc == 2) ? f2 : f3));
  float val = aggv / (ssum + 1e-16f) + sk;
  if (RES) val += hv;
  hout[(size_t)wid * 64 + lane] = f2bf(tanhf(val));
}

// ---------------- layer 3 projections (C=3): wave per node (round-7) ----------------

__global__ __launch_bounds__(256) void k_gemm3(
    const unsigned short* __restrict__ hin,
    const unsigned short* __restrict__ Wq, const unsigned short* __restrict__ bq,
    const unsigned short* __restrict__ Wk, const unsigned short* __restrict__ bk,
    const unsigned short* __restrict__ Wv, const unsigned short* __restrict__ bv,
    const unsigned short* __restrict__ Ws, const unsigned short* __restrict__ bs,
    float* __restrict__ Q3, float* __restrict__ S3, uint4* __restrict__ KV3) {
  int r = blockIdx.x * 4 + (threadIdx.x >> 6);
  int lane = threadIdx.x & 63;
  float hj = bf2f(hin[(size_t)r * 64 + lane]);
  float p[12];
#pragma unroll
  for (int c = 0; c < 3; ++c) {
    p[c]     = hj * bf2f(Wq[lane * 3 + c]);
    p[3 + c] = hj * bf2f(Wk[lane * 3 + c]);
    p[6 + c] = hj * bf2f(Wv[lane * 3 + c]);
    p[9 + c] = hj * bf2f(Ws[lane * 3 + c]);
  }
#pragma unroll
  for (int o = 32; o >= 1; o >>= 1) {
#pragma unroll
    for (int i = 0; i < 12; ++i) p[i] += __shfl_xor(p[i], o, 64);
  }
  if (lane == 0) {
    float kk[3], vv[3];
    for (int c = 0; c < 3; ++c) {
      Q3[r * 4 + c] = p[c] + bf2f(bq[c]);
      S3[r * 4 + c] = p[9 + c] + bf2f(bs[c]);
      kk[c] = p[3 + c] + bf2f(bk[c]);
      vv[c] = p[6 + c] + bf2f(bv[c]);
    }
    uint4 pk;
    pk.x = (unsigned)f2bf(kk[0]) | ((unsigned)f2bf(vv[0]) << 16);
    pk.y = (unsigned)f2bf(kk[1]) | ((unsigned)f2bf(vv[1]) << 16);
    pk.z = (unsigned)f2bf(kk[2]) | ((unsigned)f2bf(vv[2]) << 16);
    pk.w = 0;
    KV3[r] = pk;
  }
}

// ---------------- edge pass, C=3: wave per dst (round-7) ----------------

__global__ __launch_bounds__(256) void k_edge3(
    const int* __restrict__ off, const int* __restrict__ csr,
    const float* __restrict__ Q3, const float* __restrict__ S3,
    const uint4* __restrict__ KV3, const void* __restrict__ noise,
    void* __restrict__ out, const int* __restrict__ flag) {
  int w = threadIdx.x >> 6;
  int lane = threadIdx.x & 63;
  int d = blockIdx.x * 4 + w;
  int base = off[d];
  int deg = off[d + 1] - base;
  float q0 = Q3[d * 4], q1 = Q3[d * 4 + 1], q2 = Q3[d * 4 + 2];
  const float isq = 0.57735026919f;  // 1/sqrt(3)
  float m = -1e30f, ssum = 0.f, a0 = 0.f, a1 = 0.f, a2 = 0.f;
  for (int j0 = 0; j0 < deg; j0 += 64) {
    int cnt = min(64, deg - j0);
    int src = csr[base + ((lane < cnt) ? (j0 + lane) : 0)];
    uint4 kv = KV3[src];
    float sc = (q0 * lo16(kv.x) + q1 * lo16(kv.y) + q2 * lo16(kv.z)) * isq;
    sc = fminf(fmaxf(sc, -60.f), 60.f);
    if (lane >= cnt) sc = -1e30f;
    float bm = sc;
#pragma unroll
    for (int o = 32; o >= 1; o >>= 1) bm = fmaxf(bm, __shfl_xor(bm, o, 64));
    float mn = fmaxf(m, bm);
    float al = __expf(sc - mn);  // inactive lanes -> 0
    float p0 = al * hi16(kv.x);
    float p1 = al * hi16(kv.y);
    float p2 = al * hi16(kv.z);
    float bsum = al;
#pragma unroll
    for (int o = 32; o >= 1; o >>= 1) {
      bsum += __shfl_xor(bsum, o, 64);
      p0 += __shfl_xor(p0, o, 64);
      p1 += __shfl_xor(p1, o, 64);
      p2 += __shfl_xor(p2, o, 64);
    }
    float corr = __expf(m - mn);
    ssum = ssum * corr + bsum;
    a0 = a0 * corr + p0;
    a1 = a1 * corr + p1;
    a2 = a2 * corr + p2;
    m = mn;
  }
  if (lane == 0) {
    float inv = 1.f / (ssum + 1e-16f);
    int isbf = *flag;
    float n0, n1, n2;
    if (isbf) {
      const unsigned short* nu = (const unsigned short*)noise;
      n0 = bf2f(nu[d * 3 + 0]);
      n1 = bf2f(nu[d * 3 + 1]);
      n2 = bf2f(nu[d * 3 + 2]);
    } else {
      const float* nf = (const float*)noise;
      n0 = nf[d * 3 + 0];
      n1 = nf[d * 3 + 1];
      n2 = nf[d * 3 + 2];
    }
    float r0 = a0 * inv + S3[d * 4 + 0] + 0.1f * n0;
    float r1 = a1 * inv + S3[d * 4 + 1] + 0.1f * n1;
    float r2 = a2 * inv + S3[d * 4 + 2] + 0.1f * n2;
    if (isbf) {
      unsigned short* ou = (unsigned short*)out;
      ou[d * 3 + 0] = f2bf(r0);
      ou[d * 3 + 1] = f2bf(r1);
      ou[d * 3 + 2] = f2bf(r2);
    } else {
      float* of = (float*)out;
      of[d * 3 + 0] = r0;
      of[d * 3 + 1] = r1;
      of[d * 3 + 2] = r2;
    }
  }
}

// ---------------- launch ----------------

extern "C" void kernel_launch(void* const* d_in, const int* in_sizes, int n_in,
                              void* d_out, int out_size, void* d_ws, size_t ws_size,
                              hipStream_t stream) {
  const int* ei = (const int*)d_in[1];
  const int* srcs = ei;
  const int* dsts = ei + N_EDGES;

  // Workspace layout (NEED_BIG = 102868480 B, proven available in rounds 7-9):
  //   off @0 | csr @400128 | h @13200128 (bf16; CSR-build scratch aliased)
  //   kvbase @26000128: blist during build; then Kt/Vt bf16; Q3/S3/KV3 layer 3
  //   wb @51600128 | flag @51668352 | Qt f32 @51668480 | St f32 @77268480
  char* w = (char*)d_ws;
  int* off = (int*)w;
  int* csr = (int*)(w + 400128);
  char* hreg = w + 13200128;
  unsigned short* h = (unsigned short*)hreg;
  int* counts = (int*)(hreg + 524288);   // NCHUNK*NBUK ints = 611,524 B
  int* bbase = (int*)(hreg + 1200128);   // NBUK+1 ints
  int* tot = (int*)(hreg + 1310720);     // NBUK ints
  char* kvbase = w + 26000128;
  unsigned* blist = (unsigned*)kvbase;
  unsigned short* Kt = (unsigned short*)kvbase;
  unsigned short* Vt = (unsigned short*)(kvbase + 12800000);
  float* Q3 = (float*)kvbase;
  float* S3 = (float*)(kvbase + 2097152);
  uint4* KV3 = (uint4*)(kvbase + 4194304);
  unsigned short* wb = (unsigned short*)(w + 51600128);
  int* flag = (int*)(w + 51668352);
  float* Qt = (float*)(w + 51668480);
  float* St = (float*)(w + 77268480);
  const size_t NEED_BIG = 102868480;
  if (ws_size < NEED_BIG) return;

  // wb layout (shorts), per layer l in {0,1} at l*16640:
  //   PQ2 @+0, PK2 @+4096, PV2 @+8192, PS2 @+12288 (pair-packed over k)
  //   bq @+16384, bk @+16448, bv @+16512, bs @+16576
  // layer 3 @33280: Wq(192) bq(3) Wk bk Wv bv Ws bs, linear.
  CvtArgs ca;
  {
    int idx = 0;
    for (int l = 0; l < 2; ++l) {
      int base = l * 16640;
      for (int p = 0; p < 4; ++p) {  // p: 0=q,1=k,2=v,3=s
        ca.src[idx] = d_in[3 + l * 8 + p * 2];
        ca.dstoff[idx] = base + p * 4096;
        ca.n[idx] = 4096;
        ca.pp[idx] = 1;
        idx++;
        ca.src[idx] = d_in[3 + l * 8 + p * 2 + 1];
        ca.dstoff[idx] = base + 16384 + p * 64;
        ca.n[idx] = 64;
        ca.pp[idx] = 0;
        idx++;
      }
    }
    int o = 33280;  // layer 3, linear
    for (int p = 0; p < 4; ++p) {
      ca.src[idx] = d_in[3 + 16 + p * 2];
      ca.dstoff[idx] = o;
      ca.n[idx] = 192;
      ca.pp[idx] = 0;
      o += 192;
      idx++;
      ca.src[idx] = d_in[3 + 16 + p * 2 + 1];
      ca.dstoff[idx] = o;
      ca.n[idx] = 3;
      ca.pp[idx] = 0;
      o += 3;
      idx++;
    }
  }
  const unsigned* PQ20 = (const unsigned*)(wb);
  const unsigned* PK20 = (const unsigned*)(wb + 4096);
  const unsigned* PV20 = (const unsigned*)(wb + 8192);
  const unsigned* PS20 = (const unsigned*)(wb + 12288);
  const unsigned* PQ21 = (const unsigned*)(wb + 16640);
  const unsigned* PK21 = (const unsigned*)(wb + 16640 + 4096);
  const unsigned* PV21 = (const unsigned*)(wb + 16640 + 8192);
  const unsigned* PS21 = (const unsigned*)(wb + 16640 + 12288);
  const unsigned short* Bq0 = wb + 16384;
  const unsigned short* Bk0 = wb + 16448;
  const unsigned short* Bv0 = wb + 16512;
  const unsigned short* Bs0 = wb + 16576;
  const unsigned short* Bq1 = wb + 16640 + 16384;
  const unsigned short* Bk1 = wb + 16640 + 16448;
  const unsigned short* Bv1 = wb + 16640 + 16512;
  const unsigned short* Bs1 = wb + 16640 + 16576;
  const unsigned short* W3q = wb + 33280;
  const unsigned short* B3q = wb + 33472;
  const unsigned short* W3k = wb + 33475;
  const unsigned short* B3k = wb + 33667;
  const unsigned short* W3v = wb + 33670;
  const unsigned short* B3v = wb + 33862;
  const unsigned short* W3s = wb + 33865;
  const unsigned short* B3s = wb + 34057;

  k_detect<<<1, 256, 0, stream>>>((const unsigned short*)d_in[0], flag);
  k_cvt_w<<<24, 256, 0, stream>>>(ca, wb, flag);

  // CSR build (uses hreg + kvbase as scratch; must precede k_cvt_x)
  k_bhist<<<NCHUNK, 256, 0, stream>>>(dsts, counts);
  k_bscanA<<<NBUK, 64, 0, stream>>>(counts, tot);
  k_bscanB<<<1, 512, 0, stream>>>(tot, bbase);
  k_bscat<<<NCHUNK, 256, 0, stream>>>(srcs, dsts, counts, bbase, blist);
  k_bfinal<<<NBUK, 256, 0, stream>>>(blist, bbase, off, csr);

  k_cvt_x<<<(N_NODES * 8 + 511) / 512, 512, 0, stream>>>(d_in[0], h, flag);

  const int gw = N_NODES / 4;    // 25000 blocks x 4 waves (edge/gemm3/edge3)
  const int gp = N_NODES / 16;   // 6250 blocks: 25000 waves x 4 rows (gemmkvqs)
  // layer 1
  k_gemmkvqs<<<gp, 256, 0, stream>>>(h, PQ20, PK20, PV20, PS20,
                                     Bq0, Bk0, Bv0, Bs0, Kt, Vt, Qt, St);
  k_edge64b<false><<<gw, 256, 0, stream>>>(off, csr, h, Qt, St, Kt, Vt, h);
  // layer 2
  k_gemmkvqs<<<gp, 256, 0, stream>>>(h, PQ21, PK21, PV21, PS21,
                                     Bq1, Bk1, Bv1, Bs1, Kt, Vt, Qt, St);
  k_edge64b<true><<<gw, 256, 0, stream>>>(off, csr, h, Qt, St, Kt, Vt, h);
  // layer 3
  k_gemm3<<<gw, 256, 0, stream>>>(h, W3q, B3q, W3k, B3k, W3v, B3v, W3s, B3s,
                                  Q3, S3, KV3);
  k_edge3<<<gw, 256, 0, stream>>>(off, csr, Q3, S3, KV3, d_in[2], d_out, flag);
}

// Round 11
// 649.365 us; speedup vs baseline: 1.4169x; 1.0382x over previous
//
#include <hip/hip_runtime.h>

#define N_NODES 100000
#define N_EDGES 3200000
// bucket partition: bucket = dst >> 8 (256 nodes per bucket)
#define NBUK 391   // ceil(N_NODES / 256)
#define NPB 256
#define CHUNK 8192
#define NCHUNK 391  // ceil(N_EDGES / CHUNK); 391*8192 = 3,203,072 >= 3.2M

#if defined(__has_builtin)
#if __has_builtin(__builtin_amdgcn_fdot2_f32_bf16)
#define HAS_DOT2 1
#endif
#endif
#ifndef HAS_DOT2
#define HAS_DOT2 0
#endif

__device__ __forceinline__ float bf2f(unsigned short u) {
  return __uint_as_float(((unsigned)u) << 16);
}
__device__ __forceinline__ unsigned short f2bf(float f) {
  unsigned u = __float_as_uint(f);
  u += 0x7fffu + ((u >> 16) & 1u);
  return (unsigned short)(u >> 16);
}
__device__ __forceinline__ float lo16(unsigned u) { return __uint_as_float(u << 16); }
__device__ __forceinline__ float hi16(unsigned u) { return __uint_as_float(u & 0xffff0000u); }

// ---------------- dtype detection (flag=1: bf16 storage, 0: fp32) ----------------

__global__ void k_detect(const unsigned short* __restrict__ xu, int* __restrict__ flag) {
  __shared__ int cnt;
  if (threadIdx.x == 0) cnt = 0;
  __syncthreads();
  int c = 0;
  for (int i = threadIdx.x; i < 4096; i += 256) {
    float v = fabsf(bf2f(xu[2 * i]));
    if (v >= 1e-4f && v <= 10.f) c++;
  }
  atomicAdd(&cnt, c);
  __syncthreads();
  if (threadIdx.x == 0) *flag = (cnt > 2048) ? 1 : 0;
}

// ---------------- canonicalize inputs to bf16 ----------------

__global__ __launch_bounds__(512) void k_cvt_x(const void* __restrict__ x,
                                               unsigned short* __restrict__ xb,
                                               const int* __restrict__ flag) {
  int i = blockIdx.x * 512 + threadIdx.x;  // one uint4 (8 bf16) per thread
  if (i >= N_NODES * 8) return;
  if (*flag) {
    ((uint4*)xb)[i] = ((const uint4*)x)[i];
  } else {
    const float4* xf = (const float4*)x;
    float4 a = xf[2 * i], b = xf[2 * i + 1];
    uint4 o;
    o.x = (unsigned)f2bf(a.x) | ((unsigned)f2bf(a.y) << 16);
    o.y = (unsigned)f2bf(a.z) | ((unsigned)f2bf(a.w) << 16);
    o.z = (unsigned)f2bf(b.x) | ((unsigned)f2bf(b.y) << 16);
    o.w = (unsigned)f2bf(b.z) | ((unsigned)f2bf(b.w) << 16);
    ((uint4*)xb)[i] = o;
  }
}

struct CvtArgs {
  const void* src[24];
  int dstoff[24];  // in shorts
  int n[24];
  int pp[24];      // 1 = pair-pack over k for [64][64] matrix (dot2 layout)
};

// pp layout: src index i -> k=i>>6, c=i&63; dst short = (k>>1)*128 + c*2 + (k&1)
// i.e. uint word kk*64+c holds W[2kk][c] | W[2kk+1][c]<<16.
__global__ void k_cvt_w(CvtArgs a, unsigned short* __restrict__ wb,
                        const int* __restrict__ flag) {
  int b = blockIdx.x;
  const void* s = a.src[b];
  int n = a.n[b];
  int pp = a.pp[b];
  unsigned short* d = wb + a.dstoff[b];
  int isbf = *flag;
  for (int i = threadIdx.x; i < n; i += 256) {
    unsigned short v = isbf ? ((const unsigned short*)s)[i] : f2bf(((const float*)s)[i]);
    if (pp) {
      int k = i >> 6, c = i & 63;
      d[((k >> 1) << 7) + (c << 1) + (k & 1)] = v;
    } else {
      d[i] = v;
    }
  }
}

// ---------------- CSR build: two-level bucket partition ----------------

// A1: per-chunk bucket histogram
__global__ __launch_bounds__(256) void k_bhist(const int* __restrict__ dsts,
                                               int* __restrict__ counts) {
  __shared__ int hist[NBUK];
  for (int i = threadIdx.x; i < NBUK; i += 256) hist[i] = 0;
  __syncthreads();
  int e0 = blockIdx.x * CHUNK;
  int n = min(CHUNK, N_EDGES - e0);
  for (int i = threadIdx.x; i < n; i += 256)
    atomicAdd(&hist[dsts[e0 + i] >> 8], 1);
  __syncthreads();
  for (int i = threadIdx.x; i < NBUK; i += 256)
    counts[blockIdx.x * NBUK + i] = hist[i];  // chunk-major
}

// A2a: per-bucket exclusive prefix over chunks (one wave per bucket) + total
__global__ __launch_bounds__(64) void k_bscanA(int* __restrict__ counts,
                                               int* __restrict__ tot) {
  int b = blockIdx.x;
  int lane = threadIdx.x;
  int carry = 0;
  for (int c0 = 0; c0 < NCHUNK; c0 += 64) {
    int c = c0 + lane;
    int v = (c < NCHUNK) ? counts[c * NBUK + b] : 0;
    int s = v;
#pragma unroll
    for (int o = 1; o < 64; o <<= 1) {
      int u = __shfl_up(s, o, 64);
      if (lane >= o) s += u;
    }
    if (c < NCHUNK) counts[c * NBUK + b] = s - v + carry;  // bucket-local base
    carry += __shfl(s, 63, 64);
  }
  if (lane == 0) tot[b] = carry;
}

// A2b: scan bucket totals -> bbase
__global__ void k_bscanB(const int* __restrict__ tot, int* __restrict__ bbase) {
  __shared__ int s[512];
  int t = threadIdx.x;
  int v = (t < NBUK) ? tot[t] : 0;
  s[t] = v;
  __syncthreads();
  for (int o = 1; o < 512; o <<= 1) {
    int u = (t >= o) ? s[t - o] : 0;
    __syncthreads();
    s[t] += u;
    __syncthreads();
  }
  if (t <= NBUK) bbase[t] = s[t] - v;  // v==0 for t==NBUK -> total
}

// A3: rank-scatter packed (src<<8 | dst&255); bbase add folded in
__global__ __launch_bounds__(256) void k_bscat(const int* __restrict__ srcs,
                                               const int* __restrict__ dsts,
                                               const int* __restrict__ counts,
                                               const int* __restrict__ bbase,
                                               unsigned* __restrict__ blist) {
  __shared__ int cnt[NBUK];
  for (int i = threadIdx.x; i < NBUK; i += 256)
    cnt[i] = counts[blockIdx.x * NBUK + i] + bbase[i];
  __syncthreads();
  int e0 = blockIdx.x * CHUNK;
  int n = min(CHUNK, N_EDGES - e0);
  for (int i = threadIdx.x; i < n; i += 256) {
    int s = srcs[e0 + i];
    int d = dsts[e0 + i];
    int p = atomicAdd(&cnt[d >> 8], 1);
    blist[p] = ((unsigned)s << 8) | (unsigned)(d & 255);
  }
}

// B: fused per-bucket degree + scan + offset write + csr fill.
__global__ __launch_bounds__(256) void k_bfinal(const unsigned* __restrict__ blist,
                                                const int* __restrict__ bbase,
                                                int* __restrict__ off,
                                                int* __restrict__ csr) {
  __shared__ int hcnt[NPB];
  __shared__ int sc[NPB];
  int t = threadIdx.x;
  int b = blockIdx.x;
  int s = bbase[b], e = bbase[b + 1];
  hcnt[t] = 0;
  __syncthreads();
  for (int i = s + t; i < e; i += 256)
    atomicAdd(&hcnt[blist[i] & 255], 1);
  __syncthreads();
  int v = hcnt[t];
  sc[t] = v;
  __syncthreads();
  for (int o = 1; o < 256; o <<= 1) {
    int u = (t >= o) ? sc[t - o] : 0;
    __syncthreads();
    sc[t] += u;
    __syncthreads();
  }
  int my = s + sc[t] - v;  // global csr offset of this node
  int node = b * NPB + t;
  if (node < N_NODES) off[node] = my;
  if (b == 0 && t == 0) off[N_NODES] = bbase[NBUK];
  sc[t] = my;  // becomes the scatter cursor
  __syncthreads();
  for (int i = s + t; i < e; i += 256) {
    unsigned u = blist[i];
    int p = atomicAdd(&sc[u & 255], 1);
    csr[p] = (int)(u >> 8);
  }
}

// ---------------- fused K,V,Q,S projection: dot2 pair-packed, R=4 rows/wave ----
// (L2-broadcast-bound analysis r9/r10: 4 rows per wave amortizes weight-table
// reads 4x. Per-row accumulation order bit-identical.)

#if HAS_DOT2
typedef __bf16 bf16x2 __attribute__((ext_vector_type(2)));
__device__ __forceinline__ float dot2bf(unsigned h2, unsigned w2, float acc) {
  return __builtin_amdgcn_fdot2_f32_bf16(__builtin_bit_cast(bf16x2, h2),
                                         __builtin_bit_cast(bf16x2, w2), acc, false);
}
#else
__device__ __forceinline__ float dot2bf(unsigned h2, unsigned w2, float acc) {
  acc += lo16(h2) * lo16(w2);
  acc += hi16(h2) * hi16(w2);
  return acc;
}
#endif

__global__ __launch_bounds__(256) void k_gemmkvqs(
    const unsigned short* __restrict__ hin,
    const unsigned* __restrict__ PQ2, const unsigned* __restrict__ PK2,
    const unsigned* __restrict__ PV2, const unsigned* __restrict__ PS2,
    const unsigned short* __restrict__ bq, const unsigned short* __restrict__ bk,
    const unsigned short* __restrict__ bv, const unsigned short* __restrict__ bs,
    unsigned short* __restrict__ Kt, unsigned short* __restrict__ Vt,
    float* __restrict__ Qt, float* __restrict__ St) {
  int wid = blockIdx.x * 4 + (threadIdx.x >> 6);  // 25000 waves
  int lane = threadIdx.x & 63;
  int r0 = wid * 4;  // 4 consecutive rows per wave
  // lanes 0..31 hold each row's 32 bf16 pairs (lanes 32..63 duplicate)
  const unsigned* hrow = (const unsigned*)(hin + (size_t)r0 * 64);
  unsigned hp0 = hrow[lane & 31];
  unsigned hp1 = hrow[32 + (lane & 31)];
  unsigned hp2 = hrow[64 + (lane & 31)];
  unsigned hp3 = hrow[96 + (lane & 31)];
  float bqv = bf2f(bq[lane]), bkv = bf2f(bk[lane]);
  float bvv = bf2f(bv[lane]), bsv = bf2f(bs[lane]);
  float qa0 = bqv, qa1 = bqv, qa2 = bqv, qa3 = bqv;
  float ka0 = bkv, ka1 = bkv, ka2 = bkv, ka3 = bkv;
  float va0 = bvv, va1 = bvv, va2 = bvv, va3 = bvv;
  float sa0 = bsv, sa1 = bsv, sa2 = bsv, sa3 = bsv;
  for (int kk = 0; kk < 32; ++kk) {
    unsigned wq = PQ2[kk * 64 + lane];
    unsigned wk = PK2[kk * 64 + lane];
    unsigned wv = PV2[kk * 64 + lane];
    unsigned ws = PS2[kk * 64 + lane];
    unsigned hb0 = __shfl(hp0, kk, 64);
    unsigned hb1 = __shfl(hp1, kk, 64);
    unsigned hb2 = __shfl(hp2, kk, 64);
    unsigned hb3 = __shfl(hp3, kk, 64);
    qa0 = dot2bf(hb0, wq, qa0); ka0 = dot2bf(hb0, wk, ka0);
    va0 = dot2bf(hb0, wv, va0); sa0 = dot2bf(hb0, ws, sa0);
    qa1 = dot2bf(hb1, wq, qa1); ka1 = dot2bf(hb1, wk, ka1);
    va1 = dot2bf(hb1, wv, va1); sa1 = dot2bf(hb1, ws, sa1);
    qa2 = dot2bf(hb2, wq, qa2); ka2 = dot2bf(hb2, wk, ka2);
    va2 = dot2bf(hb2, wv, va2); sa2 = dot2bf(hb2, ws, sa2);
    qa3 = dot2bf(hb3, wq, qa3); ka3 = dot2bf(hb3, wk, ka3);
    va3 = dot2bf(hb3, wv, va3); sa3 = dot2bf(hb3, ws, sa3);
  }
  Kt[(size_t)(r0 + 0) * 64 + lane] = f2bf(ka0);
  Kt[(size_t)(r0 + 1) * 64 + lane] = f2bf(ka1);
  Kt[(size_t)(r0 + 2) * 64 + lane] = f2bf(ka2);
  Kt[(size_t)(r0 + 3) * 64 + lane] = f2bf(ka3);
  Vt[(size_t)(r0 + 0) * 64 + lane] = f2bf(va0);
  Vt[(size_t)(r0 + 1) * 64 + lane] = f2bf(va1);
  Vt[(size_t)(r0 + 2) * 64 + lane] = f2bf(va2);
  Vt[(size_t)(r0 + 3) * 64 + lane] = f2bf(va3);
  Qt[(size_t)(r0 + 0) * 64 + lane] = qa0;
  Qt[(size_t)(r0 + 1) * 64 + lane] = qa1;
  Qt[(size_t)(r0 + 2) * 64 + lane] = qa2;
  Qt[(size_t)(r0 + 3) * 64 + lane] = qa3;
  St[(size_t)(r0 + 0) * 64 + lane] = sa0;
  St[(size_t)(r0 + 1) * 64 + lane] = sa1;
  St[(size_t)(r0 + 2) * 64 + lane] = sa2;
  St[(size_t)(r0 + 3) * 64 + lane] = sa3;
}

// ---------------- edge pass, C=64 ----------------
// r10 diagnosis: phase 1 (lane-per-edge private 128B K-row reads) generated
// ~512 cache-line requests per 64-edge batch (8 instrs x 64 distinct lines)
// -> address-path throughput bound (~650 line-req/batch ~ measured 137us).
// Phase 1 now 8-lane-cooperative like phase 2: lane serves edge 8t+(l>>3),
// dims 8*(l&7)..+7 via one uint4 -> 16 lines/instr, 128 lines/batch. q floats
// hoisted from LDS once per wave (kills 16 per-batch LDS reads). Score
// reduce: 3-stage shfl_xor within 8-lane group + 1 collect shfl.
// Do NOT grid-stride (r8: 199us), add register pressure (r4: 289us), or
// min-waves bounds (r5: spill, 622us).

template <bool RES>
__global__ __launch_bounds__(256) void k_edge64b(
    const int* __restrict__ off, const int* __restrict__ csr,
    const unsigned short* __restrict__ hin,
    const float* __restrict__ Qt, const float* __restrict__ St,
    const unsigned short* __restrict__ Kt, const unsigned short* __restrict__ Vt,
    unsigned short* __restrict__ hout) {
  __shared__ float qs[4][64];
  int w = threadIdx.x >> 6;
  int lane = threadIdx.x & 63;
  int wid = blockIdx.x * 4 + w;
  int base = off[wid];
  int deg = off[wid + 1] - base;
  int nsrc = csr[base + ((lane < deg) ? lane : 0)];
  float q = Qt[(size_t)wid * 64 + lane];
  float sk = St[(size_t)wid * 64 + lane];
  float hv = 0.f;
  if (RES) hv = bf2f(hin[(size_t)wid * 64 + lane]);
  qs[w][lane] = q;  // wave-local write->read; lgkmcnt ordering within wave

  float m = -1e30f, ssum = 0.f;
  float4 acc = {0.f, 0.f, 0.f, 0.f};
  int g = lane >> 4;    // V-phase: edge subgroup
  int c16 = lane & 15;  // V-phase: dim-quad index
  int g8 = lane >> 3;   // K-phase: edge subgroup (8 groups of 8 lanes)
  int c8 = lane & 7;    // K-phase: dim-octet index (dims 8*c8..+7)
  const float4* qv = (const float4*)qs[w];
  // hoisted q fragments for the cooperative K-phase (once per wave)
  float4 qA = qv[2 * c8];
  float4 qB = qv[2 * c8 + 1];

  for (int j0 = 0; j0 < deg; j0 += 64) {
    int cnt = min(64, deg - j0);
    int src = nsrc;
    int nj = j0 + 64;
    if (nj < deg)
      nsrc = csr[base + nj + ((lane < deg - nj) ? lane : 0)];
    // ---- phase 1: 8-lane cooperative scores; iter t covers edges 8t..8t+7 ----
    float sc = 0.f;
    int nit = (cnt + 7) >> 3;
    for (int t = 0; t < nit; ++t) {
      int st = __shfl(src, 8 * t + g8, 64);
      uint4 kk = *(const uint4*)(Kt + (size_t)st * 64 + c8 * 8);
      float p = qA.x * lo16(kk.x) + qA.y * hi16(kk.x)
              + qA.z * lo16(kk.y) + qA.w * hi16(kk.y)
              + qB.x * lo16(kk.z) + qB.y * hi16(kk.z)
              + qB.z * lo16(kk.w) + qB.w * hi16(kk.w);
      p += __shfl_xor(p, 4, 64);
      p += __shfl_xor(p, 2, 64);
      p += __shfl_xor(p, 1, 64);
      float got = __shfl(p, (lane & 7) << 3, 64);
      if ((lane >> 3) == t) sc = got;
    }
    sc *= 0.125f;  // /sqrt(64)
    sc = fminf(fmaxf(sc, -60.f), 60.f);
    if (lane >= cnt) sc = -1e30f;
    // ---- batch softmax ----
    float bm = sc;
    bm = fmaxf(bm, __shfl_xor(bm, 32, 64));
    bm = fmaxf(bm, __shfl_xor(bm, 16, 64));
    bm = fmaxf(bm, __shfl_xor(bm, 8, 64));
    bm = fmaxf(bm, __shfl_xor(bm, 4, 64));
    bm = fmaxf(bm, __shfl_xor(bm, 2, 64));
    bm = fmaxf(bm, __shfl_xor(bm, 1, 64));
    float mn = fmaxf(m, bm);
    float al = __expf(sc - mn);
    float bsum = al;
    bsum += __shfl_xor(bsum, 32, 64);
    bsum += __shfl_xor(bsum, 16, 64);
    bsum += __shfl_xor(bsum, 8, 64);
    bsum += __shfl_xor(bsum, 4, 64);
    bsum += __shfl_xor(bsum, 2, 64);
    bsum += __shfl_xor(bsum, 1, 64);
    float corr = __expf(m - mn);
    ssum = ssum * corr + bsum;
    acc.x *= corr;
    acc.y *= corr;
    acc.z *= corr;
    acc.w *= corr;
    m = mn;
    // ---- phase 2: 4 edges per load, 16 edges (4 loads) in flight ----
    for (int jj = 0; jj < cnt; jj += 16) {
      int e0 = jj + g, e1 = jj + 4 + g, e2 = jj + 8 + g, e3 = jj + 12 + g;
      int s0 = __shfl(src, e0, 64);
      int s1 = __shfl(src, e1, 64);
      int s2 = __shfl(src, e2, 64);
      int s3 = __shfl(src, e3, 64);
      float a0 = __shfl(al, e0, 64);
      float a1 = __shfl(al, e1, 64);
      float a2 = __shfl(al, e2, 64);
      float a3 = __shfl(al, e3, 64);
      uint2 v0 = *(const uint2*)(Vt + (size_t)s0 * 64 + c16 * 4);
      uint2 v1 = *(const uint2*)(Vt + (size_t)s1 * 64 + c16 * 4);
      uint2 v2 = *(const uint2*)(Vt + (size_t)s2 * 64 + c16 * 4);
      uint2 v3 = *(const uint2*)(Vt + (size_t)s3 * 64 + c16 * 4);
      acc.x += a0 * lo16(v0.x); acc.y += a0 * hi16(v0.x);
      acc.z += a0 * lo16(v0.y); acc.w += a0 * hi16(v0.y);
      acc.x += a1 * lo16(v1.x); acc.y += a1 * hi16(v1.x);
      acc.z += a1 * lo16(v1.y); acc.w += a1 * hi16(v1.y);
      acc.x += a2 * lo16(v2.x); acc.y += a2 * hi16(v2.x);
      acc.z += a2 * lo16(v2.y); acc.w += a2 * hi16(v2.y);
      acc.x += a3 * lo16(v3.x); acc.y += a3 * hi16(v3.x);
      acc.z += a3 * lo16(v3.y); acc.w += a3 * hi16(v3.y);
    }
  }
  acc.x += __shfl_xor(acc.x, 16, 64);
  acc.y += __shfl_xor(acc.y, 16, 64);
  acc.z += __shfl_xor(acc.z, 16, 64);
  acc.w += __shfl_xor(acc.w, 16, 64);
  acc.x += __shfl_xor(acc.x, 32, 64);
  acc.y += __shfl_xor(acc.y, 32, 64);
  acc.z += __shfl_xor(acc.z, 32, 64);
  acc.w += __shfl_xor(acc.w, 32, 64);
  float f0 = __shfl(acc.x, lane >> 2, 64);
  float f1 = __shfl(acc.y, lane >> 2, 64);
  float f2 = __shfl(acc.z, lane >> 2, 64);
  float f3 = __shfl(acc.w, lane >> 2, 64);
  int cc = lane & 3;
  float aggv = (cc == 0) ? f0 : ((cc == 1) ? f1 : ((cc == 2) ? f2 : f3));
  float val = aggv / (ssum + 1e-16f) + sk;
  if (RES) val += hv;
  hout[(size_t)wid * 64 + lane] = f2bf(tanhf(val));
}

// ---------------- layer 3 projections (C=3): wave per node ----------------

__global__ __launch_bounds__(256) void k_gemm3(
    const unsigned short* __restrict__ hin,
    const unsigned short* __restrict__ Wq, const unsigned short* __restrict__ bq,
    const unsigned short* __restrict__ Wk, const unsigned short* __restrict__ bk,
    const unsigned short* __restrict__ Wv, const unsigned short* __restrict__ bv,
    const unsigned short* __restrict__ Ws, const unsigned short* __restrict__ bs,
    float* __restrict__ Q3, float* __restrict__ S3, uint4* __restrict__ KV3) {
  int r = blockIdx.x * 4 + (threadIdx.x >> 6);
  int lane = threadIdx.x & 63;
  float hj = bf2f(hin[(size_t)r * 64 + lane]);
  float p[12];
#pragma unroll
  for (int c = 0; c < 3; ++c) {
    p[c]     = hj * bf2f(Wq[lane * 3 + c]);
    p[3 + c] = hj * bf2f(Wk[lane * 3 + c]);
    p[6 + c] = hj * bf2f(Wv[lane * 3 + c]);
    p[9 + c] = hj * bf2f(Ws[lane * 3 + c]);
  }
#pragma unroll
  for (int o = 32; o >= 1; o >>= 1) {
#pragma unroll
    for (int i = 0; i < 12; ++i) p[i] += __shfl_xor(p[i], o, 64);
  }
  if (lane == 0) {
    float kk[3], vv[3];
    for (int c = 0; c < 3; ++c) {
      Q3[r * 4 + c] = p[c] + bf2f(bq[c]);
      S3[r * 4 + c] = p[9 + c] + bf2f(bs[c]);
      kk[c] = p[3 + c] + bf2f(bk[c]);
      vv[c] = p[6 + c] + bf2f(bv[c]);
    }
    uint4 pk;
    pk.x = (unsigned)f2bf(kk[0]) | ((unsigned)f2bf(vv[0]) << 16);
    pk.y = (unsigned)f2bf(kk[1]) | ((unsigned)f2bf(vv[1]) << 16);
    pk.z = (unsigned)f2bf(kk[2]) | ((unsigned)f2bf(vv[2]) << 16);
    pk.w = 0;
    KV3[r] = pk;
  }
}

// ---------------- edge pass, C=3: wave per dst ----------------

__global__ __launch_bounds__(256) void k_edge3(
    const int* __restrict__ off, const int* __restrict__ csr,
    const float* __restrict__ Q3, const float* __restrict__ S3,
    const uint4* __restrict__ KV3, const void* __restrict__ noise,
    void* __restrict__ out, const int* __restrict__ flag) {
  int w = threadIdx.x >> 6;
  int lane = threadIdx.x & 63;
  int d = blockIdx.x * 4 + w;
  int base = off[d];
  int deg = off[d + 1] - base;
  float q0 = Q3[d * 4], q1 = Q3[d * 4 + 1], q2 = Q3[d * 4 + 2];
  const float isq = 0.57735026919f;  // 1/sqrt(3)
  float m = -1e30f, ssum = 0.f, a0 = 0.f, a1 = 0.f, a2 = 0.f;
  for (int j0 = 0; j0 < deg; j0 += 64) {
    int cnt = min(64, deg - j0);
    int src = csr[base + ((lane < cnt) ? (j0 + lane) : 0)];
    uint4 kv = KV3[src];
    float sc = (q0 * lo16(kv.x) + q1 * lo16(kv.y) + q2 * lo16(kv.z)) * isq;
    sc = fminf(fmaxf(sc, -60.f), 60.f);
    if (lane >= cnt) sc = -1e30f;
    float bm = sc;
#pragma unroll
    for (int o = 32; o >= 1; o >>= 1) bm = fmaxf(bm, __shfl_xor(bm, o, 64));
    float mn = fmaxf(m, bm);
    float al = __expf(sc - mn);  // inactive lanes -> 0
    float p0 = al * hi16(kv.x);
    float p1 = al * hi16(kv.y);
    float p2 = al * hi16(kv.z);
    float bsum = al;
#pragma unroll
    for (int o = 32; o >= 1; o >>= 1) {
      bsum += __shfl_xor(bsum, o, 64);
      p0 += __shfl_xor(p0, o, 64);
      p1 += __shfl_xor(p1, o, 64);
      p2 += __shfl_xor(p2, o, 64);
    }
    float corr = __expf(m - mn);
    ssum = ssum * corr + bsum;
    a0 = a0 * corr + p0;
    a1 = a1 * corr + p1;
    a2 = a2 * corr + p2;
    m = mn;
  }
  if (lane == 0) {
    float inv = 1.f / (ssum + 1e-16f);
    int isbf = *flag;
    float n0, n1, n2;
    if (isbf) {
      const unsigned short* nu = (const unsigned short*)noise;
      n0 = bf2f(nu[d * 3 + 0]);
      n1 = bf2f(nu[d * 3 + 1]);
      n2 = bf2f(nu[d * 3 + 2]);
    } else {
      const float* nf = (const float*)noise;
      n0 = nf[d * 3 + 0];
      n1 = nf[d * 3 + 1];
      n2 = nf[d * 3 + 2];
    }
    float r0 = a0 * inv + S3[d * 4 + 0] + 0.1f * n0;
    float r1 = a1 * inv + S3[d * 4 + 1] + 0.1f * n1;
    float r2 = a2 * inv + S3[d * 4 + 2] + 0.1f * n2;
    if (isbf) {
      unsigned short* ou = (unsigned short*)out;
      ou[d * 3 + 0] = f2bf(r0);
      ou[d * 3 + 1] = f2bf(r1);
      ou[d * 3 + 2] = f2bf(r2);
    } else {
      float* of = (float*)out;
      of[d * 3 + 0] = r0;
      of[d * 3 + 1] = r1;
      of[d * 3 + 2] = r2;
    }
  }
}

// ---------------- launch ----------------

extern "C" void kernel_launch(void* const* d_in, const int* in_sizes, int n_in,
                              void* d_out, int out_size, void* d_ws, size_t ws_size,
                              hipStream_t stream) {
  const int* ei = (const int*)d_in[1];
  const int* srcs = ei;
  const int* dsts = ei + N_EDGES;

  // Workspace layout (NEED_BIG = 102868480 B, proven available rounds 7-10):
  //   off @0 | csr @400128 | h @13200128 (bf16; CSR-build scratch aliased)
  //   kvbase @26000128: blist during build; then Kt/Vt bf16; Q3/S3/KV3 layer 3
  //   wb @51600128 | flag @51668352 | Qt f32 @51668480 | St f32 @77268480
  char* w = (char*)d_ws;
  int* off = (int*)w;
  int* csr = (int*)(w + 400128);
  char* hreg = w + 13200128;
  unsigned short* h = (unsigned short*)hreg;
  int* counts = (int*)(hreg + 524288);   // NCHUNK*NBUK ints = 611,524 B
  int* bbase = (int*)(hreg + 1200128);   // NBUK+1 ints
  int* tot = (int*)(hreg + 1310720);     // NBUK ints
  char* kvbase = w + 26000128;
  unsigned* blist = (unsigned*)kvbase;
  unsigned short* Kt = (unsigned short*)kvbase;
  unsigned short* Vt = (unsigned short*)(kvbase + 12800000);
  float* Q3 = (float*)kvbase;
  float* S3 = (float*)(kvbase + 2097152);
  uint4* KV3 = (uint4*)(kvbase + 4194304);
  unsigned short* wb = (unsigned short*)(w + 51600128);
  int* flag = (int*)(w + 51668352);
  float* Qt = (float*)(w + 51668480);
  float* St = (float*)(w + 77268480);
  const size_t NEED_BIG = 102868480;
  if (ws_size < NEED_BIG) return;

  // wb layout (shorts), per layer l in {0,1} at l*16640:
  //   PQ2 @+0, PK2 @+4096, PV2 @+8192, PS2 @+12288 (pair-packed over k)
  //   bq @+16384, bk @+16448, bv @+16512, bs @+16576
  // layer 3 @33280: Wq(192) bq(3) Wk bk Wv bv Ws bs, linear.
  CvtArgs ca;
  {
    int idx = 0;
    for (int l = 0; l < 2; ++l) {
      int base = l * 16640;
      for (int p = 0; p < 4; ++p) {  // p: 0=q,1=k,2=v,3=s
        ca.src[idx] = d_in[3 + l * 8 + p * 2];
        ca.dstoff[idx] = base + p * 4096;
        ca.n[idx] = 4096;
        ca.pp[idx] = 1;
        idx++;
        ca.src[idx] = d_in[3 + l * 8 + p * 2 + 1];
        ca.dstoff[idx] = base + 16384 + p * 64;
        ca.n[idx] = 64;
        ca.pp[idx] = 0;
        idx++;
      }
    }
    int o = 33280;  // layer 3, linear
    for (int p = 0; p < 4; ++p) {
      ca.src[idx] = d_in[3 + 16 + p * 2];
      ca.dstoff[idx] = o;
      ca.n[idx] = 192;
      ca.pp[idx] = 0;
      o += 192;
      idx++;
      ca.src[idx] = d_in[3 + 16 + p * 2 + 1];
      ca.dstoff[idx] = o;
      ca.n[idx] = 3;
      ca.pp[idx] = 0;
      o += 3;
      idx++;
    }
  }
  const unsigned* PQ20 = (const unsigned*)(wb);
  const unsigned* PK20 = (const unsigned*)(wb + 4096);
  const unsigned* PV20 = (const unsigned*)(wb + 8192);
  const unsigned* PS20 = (const unsigned*)(wb + 12288);
  const unsigned* PQ21 = (const unsigned*)(wb + 16640);
  const unsigned* PK21 = (const unsigned*)(wb + 16640 + 4096);
  const unsigned* PV21 = (const unsigned*)(wb + 16640 + 8192);
  const unsigned* PS21 = (const unsigned*)(wb + 16640 + 12288);
  const unsigned short* Bq0 = wb + 16384;
  const unsigned short* Bk0 = wb + 16448;
  const unsigned short* Bv0 = wb + 16512;
  const unsigned short* Bs0 = wb + 16576;
  const unsigned short* Bq1 = wb + 16640 + 16384;
  const unsigned short* Bk1 = wb + 16640 + 16448;
  const unsigned short* Bv1 = wb + 16640 + 16512;
  const unsigned short* Bs1 = wb + 16640 + 16576;
  const unsigned short* W3q = wb + 33280;
  const unsigned short* B3q = wb + 33472;
  const unsigned short* W3k = wb + 33475;
  const unsigned short* B3k = wb + 33667;
  const unsigned short* W3v = wb + 33670;
  const unsigned short* B3v = wb + 33862;
  const unsigned short* W3s = wb + 33865;
  const unsigned short* B3s = wb + 34057;

  k_detect<<<1, 256, 0, stream>>>((const unsigned short*)d_in[0], flag);
  k_cvt_w<<<24, 256, 0, stream>>>(ca, wb, flag);

  // CSR build (uses hreg + kvbase as scratch; must precede k_cvt_x)
  k_bhist<<<NCHUNK, 256, 0, stream>>>(dsts, counts);
  k_bscanA<<<NBUK, 64, 0, stream>>>(counts, tot);
  k_bscanB<<<1, 512, 0, stream>>>(tot, bbase);
  k_bscat<<<NCHUNK, 256, 0, stream>>>(srcs, dsts, counts, bbase, blist);
  k_bfinal<<<NBUK, 256, 0, stream>>>(blist, bbase, off, csr);

  k_cvt_x<<<(N_NODES * 8 + 511) / 512, 512, 0, stream>>>(d_in[0], h, flag);

  const int gw = N_NODES / 4;    // 25000 blocks x 4 waves (edge/gemm3/edge3)
  const int gp = N_NODES / 16;   // 6250 blocks: 25000 waves x 4 rows (gemmkvqs)
  // layer 1
  k_gemmkvqs<<<gp, 256, 0, stream>>>(h, PQ20, PK20, PV20, PS20,
                                     Bq0, Bk0, Bv0, Bs0, Kt, Vt, Qt, St);
  k_edge64b<false><<<gw, 256, 0, stream>>>(off, csr, h, Qt, St, Kt, Vt, h);
  // layer 2
  k_gemmkvqs<<<gp, 256, 0, stream>>>(h, PQ21, PK21, PV21, PS21,
                                     Bq1, Bk1, Bv1, Bs1, Kt, Vt, Qt, St);
  k_edge64b<true><<<gw, 256, 0, stream>>>(off, csr, h, Qt, St, Kt, Vt, h);
  // layer 3
  k_gemm3<<<gw, 256, 0, stream>>>(h, W3q, B3q, W3k, B3k, W3v, B3v, W3s, B3s,
                                  Q3, S3, KV3);
  k_edge3<<<gw, 256, 0, stream>>>(off, csr, Q3, S3, KV3, d_in[2], d_out, flag);
}

// Round 12
// 592.156 us; speedup vs baseline: 1.5538x; 1.0966x over previous
//
#include <hip/hip_runtime.h>

#define N_NODES 100000
#define N_EDGES 3200000
// bucket partition: bucket = dst >> 8 (256 nodes per bucket)
#define NBUK 391   // ceil(N_NODES / 256)
#define NPB 256
#define CHUNK 8192
#define NCHUNK 391  // ceil(N_EDGES / CHUNK); 391*8192 = 3,203,072 >= 3.2M

#if defined(__has_builtin)
#if __has_builtin(__builtin_amdgcn_fdot2_f32_bf16)
#define HAS_DOT2 1
#endif
#endif
#ifndef HAS_DOT2
#define HAS_DOT2 0
#endif

__device__ __forceinline__ float bf2f(unsigned short u) {
  return __uint_as_float(((unsigned)u) << 16);
}
__device__ __forceinline__ unsigned short f2bf(float f) {
  unsigned u = __float_as_uint(f);
  u += 0x7fffu + ((u >> 16) & 1u);
  return (unsigned short)(u >> 16);
}
__device__ __forceinline__ float lo16(unsigned u) { return __uint_as_float(u << 16); }
__device__ __forceinline__ float hi16(unsigned u) { return __uint_as_float(u & 0xffff0000u); }

// ---------------- dtype detection (flag=1: bf16 storage, 0: fp32) ----------------

__global__ void k_detect(const unsigned short* __restrict__ xu, int* __restrict__ flag) {
  __shared__ int cnt;
  if (threadIdx.x == 0) cnt = 0;
  __syncthreads();
  int c = 0;
  for (int i = threadIdx.x; i < 4096; i += 256) {
    float v = fabsf(bf2f(xu[2 * i]));
    if (v >= 1e-4f && v <= 10.f) c++;
  }
  atomicAdd(&cnt, c);
  __syncthreads();
  if (threadIdx.x == 0) *flag = (cnt > 2048) ? 1 : 0;
}

struct CvtArgs {
  const void* src[24];
  int dstoff[24];  // in shorts
  int n[24];
  int pp[24];      // 0=linear; 1=pair-pack [64][64]; >=3: layer3 combined, toff=pp-3
};

// pp=1: src i -> k=i>>6, c=i&63; dst short = (k>>1)*128 + c*2 + (k&1)
//       (uint word kk*64+c holds W[2kk][c] | W[2kk+1][c]<<16)
// pp>=3: layer-3 [64][3] table into combined pair-packed [32 pairs][12] table:
//       i -> d=i/3, c=i%3 + (pp-3); dst short = (d>>1)*24 + c*2 + (d&1)
__global__ void k_cvt_w(CvtArgs a, unsigned short* __restrict__ wb,
                        const int* __restrict__ flag) {
  int b = blockIdx.x;
  const void* s = a.src[b];
  int n = a.n[b];
  int pp = a.pp[b];
  unsigned short* d = wb + a.dstoff[b];
  int isbf = *flag;
  for (int i = threadIdx.x; i < n; i += 256) {
    unsigned short v = isbf ? ((const unsigned short*)s)[i] : f2bf(((const float*)s)[i]);
    if (pp == 1) {
      int k = i >> 6, c = i & 63;
      d[((k >> 1) << 7) + (c << 1) + (k & 1)] = v;
    } else if (pp >= 3) {
      int dd = i / 3, c = i % 3 + (pp - 3);
      d[(dd >> 1) * 24 + (c << 1) + (dd & 1)] = v;
    } else {
      d[i] = v;
    }
  }
}

// ---------------- CSR build: two-level bucket partition ----------------

// A1: per-chunk bucket histogram
__global__ __launch_bounds__(256) void k_bhist(const int* __restrict__ dsts,
                                               int* __restrict__ counts) {
  __shared__ int hist[NBUK];
  for (int i = threadIdx.x; i < NBUK; i += 256) hist[i] = 0;
  __syncthreads();
  int e0 = blockIdx.x * CHUNK;
  int n = min(CHUNK, N_EDGES - e0);
  for (int i = threadIdx.x; i < n; i += 256)
    atomicAdd(&hist[dsts[e0 + i] >> 8], 1);
  __syncthreads();
  for (int i = threadIdx.x; i < NBUK; i += 256)
    counts[blockIdx.x * NBUK + i] = hist[i];  // chunk-major
}

// A2a: per-bucket exclusive prefix over chunks (one wave per bucket) + total
__global__ __launch_bounds__(64) void k_bscanA(int* __restrict__ counts,
                                               int* __restrict__ tot) {
  int b = blockIdx.x;
  int lane = threadIdx.x;
  int carry = 0;
  for (int c0 = 0; c0 < NCHUNK; c0 += 64) {
    int c = c0 + lane;
    int v = (c < NCHUNK) ? counts[c * NBUK + b] : 0;
    int s = v;
#pragma unroll
    for (int o = 1; o < 64; o <<= 1) {
      int u = __shfl_up(s, o, 64);
      if (lane >= o) s += u;
    }
    if (c < NCHUNK) counts[c * NBUK + b] = s - v + carry;  // bucket-local base
    carry += __shfl(s, 63, 64);
  }
  if (lane == 0) tot[b] = carry;
}

// A2b: scan bucket totals -> bbase
__global__ void k_bscanB(const int* __restrict__ tot, int* __restrict__ bbase) {
  __shared__ int s[512];
  int t = threadIdx.x;
  int v = (t < NBUK) ? tot[t] : 0;
  s[t] = v;
  __syncthreads();
  for (int o = 1; o < 512; o <<= 1) {
    int u = (t >= o) ? s[t - o] : 0;
    __syncthreads();
    s[t] += u;
    __syncthreads();
  }
  if (t <= NBUK) bbase[t] = s[t] - v;  // v==0 for t==NBUK -> total
}

// A3: rank-scatter packed (src<<8 | dst&255); bbase add folded in
__global__ __launch_bounds__(256) void k_bscat(const int* __restrict__ srcs,
                                               const int* __restrict__ dsts,
                                               const int* __restrict__ counts,
                                               const int* __restrict__ bbase,
                                               unsigned* __restrict__ blist) {
  __shared__ int cnt[NBUK];
  for (int i = threadIdx.x; i < NBUK; i += 256)
    cnt[i] = counts[blockIdx.x * NBUK + i] + bbase[i];
  __syncthreads();
  int e0 = blockIdx.x * CHUNK;
  int n = min(CHUNK, N_EDGES - e0);
  for (int i = threadIdx.x; i < n; i += 256) {
    int s = srcs[e0 + i];
    int d = dsts[e0 + i];
    int p = atomicAdd(&cnt[d >> 8], 1);
    blist[p] = ((unsigned)s << 8) | (unsigned)(d & 255);
  }
}

// B: fused per-bucket degree + scan + offset write + csr fill.
__global__ __launch_bounds__(256) void k_bfinal(const unsigned* __restrict__ blist,
                                                const int* __restrict__ bbase,
                                                int* __restrict__ off,
                                                int* __restrict__ csr) {
  __shared__ int hcnt[NPB];
  __shared__ int sc[NPB];
  int t = threadIdx.x;
  int b = blockIdx.x;
  int s = bbase[b], e = bbase[b + 1];
  hcnt[t] = 0;
  __syncthreads();
  for (int i = s + t; i < e; i += 256)
    atomicAdd(&hcnt[blist[i] & 255], 1);
  __syncthreads();
  int v = hcnt[t];
  sc[t] = v;
  __syncthreads();
  for (int o = 1; o < 256; o <<= 1) {
    int u = (t >= o) ? sc[t - o] : 0;
    __syncthreads();
    sc[t] += u;
    __syncthreads();
  }
  int my = s + sc[t] - v;  // global csr offset of this node
  int node = b * NPB + t;
  if (node < N_NODES) off[node] = my;
  if (b == 0 && t == 0) off[N_NODES] = bbase[NBUK];
  sc[t] = my;  // becomes the scatter cursor
  __syncthreads();
  for (int i = s + t; i < e; i += 256) {
    unsigned u = blist[i];
    int p = atomicAdd(&sc[u & 255], 1);
    csr[p] = (int)(u >> 8);
  }
}

// ---------------- fused K,V,Q,S projection: dot2 pair-packed, R=8 rows/wave ----
// r10/r11: this kernel is L2-broadcast-bandwidth-bound on weight-table reads.
// R=4 halved it once; R=8 halves again (0.41 GB ~ 12us) leaving ~16us VALU.
// Layer 1 reads raw x with inline f2bf conversion (bit-identical to the old
// k_cvt_x output), removing that kernel entirely. Per-row accumulation order
// bit-identical to rounds 9-11.

#if HAS_DOT2
typedef __bf16 bf16x2 __attribute__((ext_vector_type(2)));
__device__ __forceinline__ float dot2bf(unsigned h2, unsigned w2, float acc) {
  return __builtin_amdgcn_fdot2_f32_bf16(__builtin_bit_cast(bf16x2, h2),
                                         __builtin_bit_cast(bf16x2, w2), acc, false);
}
#else
__device__ __forceinline__ float dot2bf(unsigned h2, unsigned w2, float acc) {
  acc += lo16(h2) * lo16(w2);
  acc += hi16(h2) * hi16(w2);
  return acc;
}
#endif

template <bool L1>
__global__ __launch_bounds__(256) void k_gemmkvqs(
    const void* __restrict__ xin, const int* __restrict__ flag,
    const unsigned* __restrict__ PQ2, const unsigned* __restrict__ PK2,
    const unsigned* __restrict__ PV2, const unsigned* __restrict__ PS2,
    const unsigned short* __restrict__ bq, const unsigned short* __restrict__ bk,
    const unsigned short* __restrict__ bv, const unsigned short* __restrict__ bs,
    unsigned short* __restrict__ Kt, unsigned short* __restrict__ Vt,
    float* __restrict__ Qt, float* __restrict__ St) {
  int wid = blockIdx.x * 4 + (threadIdx.x >> 6);  // 12500 waves
  int lane = threadIdx.x & 63;
  int r0 = wid * 8;  // 8 consecutive rows per wave
  int l31 = lane & 31;
  unsigned hp[8];
  bool cvt = L1 && (*flag == 0);
  if (cvt) {
    const float2* xf = (const float2*)xin;
#pragma unroll
    for (int j = 0; j < 8; ++j) {
      float2 v = xf[(size_t)(r0 + j) * 32 + l31];
      hp[j] = (unsigned)f2bf(v.x) | ((unsigned)f2bf(v.y) << 16);
    }
  } else {
    const unsigned* hu = (const unsigned*)xin;
#pragma unroll
    for (int j = 0; j < 8; ++j)
      hp[j] = hu[(size_t)(r0 + j) * 32 + l31];
  }
  float bqv = bf2f(bq[lane]), bkv = bf2f(bk[lane]);
  float bvv = bf2f(bv[lane]), bsv = bf2f(bs[lane]);
  float qa[8], ka[8], va[8], sa[8];
#pragma unroll
  for (int j = 0; j < 8; ++j) {
    qa[j] = bqv;
    ka[j] = bkv;
    va[j] = bvv;
    sa[j] = bsv;
  }
  for (int kk = 0; kk < 32; ++kk) {
    unsigned wq = PQ2[kk * 64 + lane];
    unsigned wk = PK2[kk * 64 + lane];
    unsigned wv = PV2[kk * 64 + lane];
    unsigned ws = PS2[kk * 64 + lane];
#pragma unroll
    for (int j = 0; j < 8; ++j) {
      unsigned hb = __shfl(hp[j], kk, 64);
      qa[j] = dot2bf(hb, wq, qa[j]);
      ka[j] = dot2bf(hb, wk, ka[j]);
      va[j] = dot2bf(hb, wv, va[j]);
      sa[j] = dot2bf(hb, ws, sa[j]);
    }
  }
#pragma unroll
  for (int j = 0; j < 8; ++j) {
    Kt[(size_t)(r0 + j) * 64 + lane] = f2bf(ka[j]);
    Vt[(size_t)(r0 + j) * 64 + lane] = f2bf(va[j]);
    Qt[(size_t)(r0 + j) * 64 + lane] = qa[j];
    St[(size_t)(r0 + j) * 64 + lane] = sa[j];
  }
}

// ---------------- edge pass, C=64 ----------------
// r11 structure (cooperative phase 1, best: 121us @ 40 VGPR), with the LDS
// q-staging replaced by 8 one-time register shuffles -> kills the 888K
// SQ_LDS_BANK_CONFLICT and all LDS use. Do NOT grid-stride (r8: 199us), add
// register pressure (r4: 289us), or min-waves bounds (r5: spill, 622us).

template <bool RES>
__global__ __launch_bounds__(256) void k_edge64b(
    const int* __restrict__ off, const int* __restrict__ csr,
    const unsigned short* __restrict__ hin,
    const float* __restrict__ Qt, const float* __restrict__ St,
    const unsigned short* __restrict__ Kt, const unsigned short* __restrict__ Vt,
    unsigned short* __restrict__ hout) {
  int w = threadIdx.x >> 6;
  int lane = threadIdx.x & 63;
  int wid = blockIdx.x * 4 + w;
  int base = off[wid];
  int deg = off[wid + 1] - base;
  int nsrc = csr[base + ((lane < deg) ? lane : 0)];
  float q = Qt[(size_t)wid * 64 + lane];
  float sk = St[(size_t)wid * 64 + lane];
  float hv = 0.f;
  if (RES) hv = bf2f(hin[(size_t)wid * 64 + lane]);

  float m = -1e30f, ssum = 0.f;
  float4 acc = {0.f, 0.f, 0.f, 0.f};
  int g = lane >> 4;    // V-phase: edge subgroup
  int c16 = lane & 15;  // V-phase: dim-quad index
  int g8 = lane >> 3;   // K-phase: edge subgroup (8 groups of 8 lanes)
  int c8 = lane & 7;    // K-phase: dim-octet index (dims 8*c8..+7)
  // q fragments for the cooperative K-phase via register shuffles (no LDS)
  int b8 = c8 << 3;
  float4 qA, qB;
  qA.x = __shfl(q, b8 + 0, 64);
  qA.y = __shfl(q, b8 + 1, 64);
  qA.z = __shfl(q, b8 + 2, 64);
  qA.w = __shfl(q, b8 + 3, 64);
  qB.x = __shfl(q, b8 + 4, 64);
  qB.y = __shfl(q, b8 + 5, 64);
  qB.z = __shfl(q, b8 + 6, 64);
  qB.w = __shfl(q, b8 + 7, 64);

  for (int j0 = 0; j0 < deg; j0 += 64) {
    int cnt = min(64, deg - j0);
    int src = nsrc;
    int nj = j0 + 64;
    if (nj < deg)
      nsrc = csr[base + nj + ((lane < deg - nj) ? lane : 0)];
    // ---- phase 1: 8-lane cooperative scores; iter t covers edges 8t..8t+7 ----
    float sc = 0.f;
    int nit = (cnt + 7) >> 3;
    for (int t = 0; t < nit; ++t) {
      int st = __shfl(src, 8 * t + g8, 64);
      uint4 kk = *(const uint4*)(Kt + (size_t)st * 64 + c8 * 8);
      float p = qA.x * lo16(kk.x) + qA.y * hi16(kk.x)
              + qA.z * lo16(kk.y) + qA.w * hi16(kk.y)
              + qB.x * lo16(kk.z) + qB.y * hi16(kk.z)
              + qB.z * lo16(kk.w) + qB.w * hi16(kk.w);
      p += __shfl_xor(p, 4, 64);
      p += __shfl_xor(p, 2, 64);
      p += __shfl_xor(p, 1, 64);
      float got = __shfl(p, (lane & 7) << 3, 64);
      if ((lane >> 3) == t) sc = got;
    }
    sc *= 0.125f;  // /sqrt(64)
    sc = fminf(fmaxf(sc, -60.f), 60.f);
    if (lane >= cnt) sc = -1e30f;
    // ---- batch softmax ----
    float bm = sc;
    bm = fmaxf(bm, __shfl_xor(bm, 32, 64));
    bm = fmaxf(bm, __shfl_xor(bm, 16, 64));
    bm = fmaxf(bm, __shfl_xor(bm, 8, 64));
    bm = fmaxf(bm, __shfl_xor(bm, 4, 64));
    bm = fmaxf(bm, __shfl_xor(bm, 2, 64));
    bm = fmaxf(bm, __shfl_xor(bm, 1, 64));
    float mn = fmaxf(m, bm);
    float al = __expf(sc - mn);
    float bsum = al;
    bsum += __shfl_xor(bsum, 32, 64);
    bsum += __shfl_xor(bsum, 16, 64);
    bsum += __shfl_xor(bsum, 8, 64);
    bsum += __shfl_xor(bsum, 4, 64);
    bsum += __shfl_xor(bsum, 2, 64);
    bsum += __shfl_xor(bsum, 1, 64);
    float corr = __expf(m - mn);
    ssum = ssum * corr + bsum;
    acc.x *= corr;
    acc.y *= corr;
    acc.z *= corr;
    acc.w *= corr;
    m = mn;
    // ---- phase 2: 4 edges per load, 16 edges (4 loads) in flight ----
    for (int jj = 0; jj < cnt; jj += 16) {
      int e0 = jj + g, e1 = jj + 4 + g, e2 = jj + 8 + g, e3 = jj + 12 + g;
      int s0 = __shfl(src, e0, 64);
      int s1 = __shfl(src, e1, 64);
      int s2 = __shfl(src, e2, 64);
      int s3 = __shfl(src, e3, 64);
      float a0 = __shfl(al, e0, 64);
      float a1 = __shfl(al, e1, 64);
      float a2 = __shfl(al, e2, 64);
      float a3 = __shfl(al, e3, 64);
      uint2 v0 = *(const uint2*)(Vt + (size_t)s0 * 64 + c16 * 4);
      uint2 v1 = *(const uint2*)(Vt + (size_t)s1 * 64 + c16 * 4);
      uint2 v2 = *(const uint2*)(Vt + (size_t)s2 * 64 + c16 * 4);
      uint2 v3 = *(const uint2*)(Vt + (size_t)s3 * 64 + c16 * 4);
      acc.x += a0 * lo16(v0.x); acc.y += a0 * hi16(v0.x);
      acc.z += a0 * lo16(v0.y); acc.w += a0 * hi16(v0.y);
      acc.x += a1 * lo16(v1.x); acc.y += a1 * hi16(v1.x);
      acc.z += a1 * lo16(v1.y); acc.w += a1 * hi16(v1.y);
      acc.x += a2 * lo16(v2.x); acc.y += a2 * hi16(v2.x);
      acc.z += a2 * lo16(v2.y); acc.w += a2 * hi16(v2.y);
      acc.x += a3 * lo16(v3.x); acc.y += a3 * hi16(v3.x);
      acc.z += a3 * lo16(v3.y); acc.w += a3 * hi16(v3.y);
    }
  }
  acc.x += __shfl_xor(acc.x, 16, 64);
  acc.y += __shfl_xor(acc.y, 16, 64);
  acc.z += __shfl_xor(acc.z, 16, 64);
  acc.w += __shfl_xor(acc.w, 16, 64);
  acc.x += __shfl_xor(acc.x, 32, 64);
  acc.y += __shfl_xor(acc.y, 32, 64);
  acc.z += __shfl_xor(acc.z, 32, 64);
  acc.w += __shfl_xor(acc.w, 32, 64);
  float f0 = __shfl(acc.x, lane >> 2, 64);
  float f1 = __shfl(acc.y, lane >> 2, 64);
  float f2 = __shfl(acc.z, lane >> 2, 64);
  float f3 = __shfl(acc.w, lane >> 2, 64);
  int cc = lane & 3;
  float aggv = (cc == 0) ? f0 : ((cc == 1) ? f1 : ((cc == 2) ? f2 : f3));
  float val = aggv / (ssum + 1e-16f) + sk;
  if (RES) val += hv;
  hout[(size_t)wid * 64 + lane] = f2bf(tanhf(val));
}

// ---------------- layer 3 projections (C=3): 4-lane group per node ----------------
// 16 nodes/wave; lane (g=lane>>2, q4=lane&3) handles node g, dims q4*16..+15
// via 8 bf16 pairs against the combined pair-packed [32][12] weight table
// (cols 0-2=q, 3-5=k, 6-8=v, 9-11=s). 2-stage butterfly reduce within the
// 4-lane group. (Old wave-per-node version spent 72 shfls per node.)

__global__ __launch_bounds__(256) void k_gemm3(
    const unsigned short* __restrict__ hin, const unsigned* __restrict__ W12p,
    const unsigned short* __restrict__ bq, const unsigned short* __restrict__ bk,
    const unsigned short* __restrict__ bv, const unsigned short* __restrict__ bs,
    float* __restrict__ Q3, float* __restrict__ S3, uint4* __restrict__ KV3) {
  int w = threadIdx.x >> 6;
  int lane = threadIdx.x & 63;
  int g = lane >> 2, q4 = lane & 3;
  int node = blockIdx.x * 64 + w * 16 + g;
  if (node >= N_NODES) return;  // whole 4-lane group exits together
  const uint4* hp = (const uint4*)(hin + (size_t)node * 64 + q4 * 16);
  uint4 h0 = hp[0], h1 = hp[1];
  unsigned hu[8] = {h0.x, h0.y, h0.z, h0.w, h1.x, h1.y, h1.z, h1.w};
  float a[12];
#pragma unroll
  for (int c = 0; c < 12; ++c) a[c] = 0.f;
#pragma unroll
  for (int j = 0; j < 8; ++j) {
    int pr = q4 * 8 + j;  // bf16-pair index (dims 2pr, 2pr+1)
    const uint4* wp = (const uint4*)(W12p + pr * 12);
    uint4 wa = wp[0], wbv = wp[1], wc = wp[2];
    unsigned wu[12] = {wa.x, wa.y, wa.z, wa.w, wbv.x, wbv.y,
                       wbv.z, wbv.w, wc.x, wc.y, wc.z, wc.w};
#pragma unroll
    for (int c = 0; c < 12; ++c) a[c] = dot2bf(hu[j], wu[c], a[c]);
  }
#pragma unroll
  for (int c = 0; c < 12; ++c) {
    a[c] += __shfl_xor(a[c], 1, 64);
    a[c] += __shfl_xor(a[c], 2, 64);
  }
  if (q4 == 0) {
    for (int c = 0; c < 3; ++c) Q3[node * 4 + c] = a[c] + bf2f(bq[c]);
  } else if (q4 == 1) {
    for (int c = 0; c < 3; ++c) S3[node * 4 + c] = a[9 + c] + bf2f(bs[c]);
  } else if (q4 == 2) {
    float kk[3], vv[3];
    for (int c = 0; c < 3; ++c) {
      kk[c] = a[3 + c] + bf2f(bk[c]);
      vv[c] = a[6 + c] + bf2f(bv[c]);
    }
    uint4 pk;
    pk.x = (unsigned)f2bf(kk[0]) | ((unsigned)f2bf(vv[0]) << 16);
    pk.y = (unsigned)f2bf(kk[1]) | ((unsigned)f2bf(vv[1]) << 16);
    pk.z = (unsigned)f2bf(kk[2]) | ((unsigned)f2bf(vv[2]) << 16);
    pk.w = 0;
    KV3[node] = pk;
  }
}

// ---------------- edge pass, C=3: wave per dst ----------------

__global__ __launch_bounds__(256) void k_edge3(
    const int* __restrict__ off, const int* __restrict__ csr,
    const float* __restrict__ Q3, const float* __restrict__ S3,
    const uint4* __restrict__ KV3, const void* __restrict__ noise,
    void* __restrict__ out, const int* __restrict__ flag) {
  int w = threadIdx.x >> 6;
  int lane = threadIdx.x & 63;
  int d = blockIdx.x * 4 + w;
  int base = off[d];
  int deg = off[d + 1] - base;
  float q0 = Q3[d * 4], q1 = Q3[d * 4 + 1], q2 = Q3[d * 4 + 2];
  const float isq = 0.57735026919f;  // 1/sqrt(3)
  float m = -1e30f, ssum = 0.f, a0 = 0.f, a1 = 0.f, a2 = 0.f;
  for (int j0 = 0; j0 < deg; j0 += 64) {
    int cnt = min(64, deg - j0);
    int src = csr[base + ((lane < cnt) ? (j0 + lane) : 0)];
    uint4 kv = KV3[src];
    float sc = (q0 * lo16(kv.x) + q1 * lo16(kv.y) + q2 * lo16(kv.z)) * isq;
    sc = fminf(fmaxf(sc, -60.f), 60.f);
    if (lane >= cnt) sc = -1e30f;
    float bm = sc;
#pragma unroll
    for (int o = 32; o >= 1; o >>= 1) bm = fmaxf(bm, __shfl_xor(bm, o, 64));
    float mn = fmaxf(m, bm);
    float al = __expf(sc - mn);  // inactive lanes -> 0
    float p0 = al * hi16(kv.x);
    float p1 = al * hi16(kv.y);
    float p2 = al * hi16(kv.z);
    float bsum = al;
#pragma unroll
    for (int o = 32; o >= 1; o >>= 1) {
      bsum += __shfl_xor(bsum, o, 64);
      p0 += __shfl_xor(p0, o, 64);
      p1 += __shfl_xor(p1, o, 64);
      p2 += __shfl_xor(p2, o, 64);
    }
    float corr = __expf(m - mn);
    ssum = ssum * corr + bsum;
    a0 = a0 * corr + p0;
    a1 = a1 * corr + p1;
    a2 = a2 * corr + p2;
    m = mn;
  }
  if (lane == 0) {
    float inv = 1.f / (ssum + 1e-16f);
    int isbf = *flag;
    float n0, n1, n2;
    if (isbf) {
      const unsigned short* nu = (const unsigned short*)noise;
      n0 = bf2f(nu[d * 3 + 0]);
      n1 = bf2f(nu[d * 3 + 1]);
      n2 = bf2f(nu[d * 3 + 2]);
    } else {
      const float* nf = (const float*)noise;
      n0 = nf[d * 3 + 0];
      n1 = nf[d * 3 + 1];
      n2 = nf[d * 3 + 2];
    }
    float r0 = a0 * inv + S3[d * 4 + 0] + 0.1f * n0;
    float r1 = a1 * inv + S3[d * 4 + 1] + 0.1f * n1;
    float r2 = a2 * inv + S3[d * 4 + 2] + 0.1f * n2;
    if (isbf) {
      unsigned short* ou = (unsigned short*)out;
      ou[d * 3 + 0] = f2bf(r0);
      ou[d * 3 + 1] = f2bf(r1);
      ou[d * 3 + 2] = f2bf(r2);
    } else {
      float* of = (float*)out;
      of[d * 3 + 0] = r0;
      of[d * 3 + 1] = r1;
      of[d * 3 + 2] = r2;
    }
  }
}

// ---------------- launch ----------------

extern "C" void kernel_launch(void* const* d_in, const int* in_sizes, int n_in,
                              void* d_out, int out_size, void* d_ws, size_t ws_size,
                              hipStream_t stream) {
  const int* ei = (const int*)d_in[1];
  const int* srcs = ei;
  const int* dsts = ei + N_EDGES;

  // Workspace layout (NEED_BIG = 102868480 B, proven available rounds 7-11):
  //   off @0 | csr @400128 | h @13200128 (bf16; CSR-build scratch aliased)
  //   kvbase @26000128: blist during build; then Kt/Vt bf16; Q3/S3/KV3 layer 3
  //   wb @51600128 | flag @51668352 | Qt f32 @51668480 | St f32 @77268480
  char* w = (char*)d_ws;
  int* off = (int*)w;
  int* csr = (int*)(w + 400128);
  char* hreg = w + 13200128;
  unsigned short* h = (unsigned short*)hreg;
  int* counts = (int*)(hreg + 524288);   // NCHUNK*NBUK ints = 611,524 B
  int* bbase = (int*)(hreg + 1200128);   // NBUK+1 ints
  int* tot = (int*)(hreg + 1310720);     // NBUK ints
  char* kvbase = w + 26000128;
  unsigned* blist = (unsigned*)kvbase;
  unsigned short* Kt = (unsigned short*)kvbase;
  unsigned short* Vt = (unsigned short*)(kvbase + 12800000);
  float* Q3 = (float*)kvbase;
  float* S3 = (float*)(kvbase + 2097152);
  uint4* KV3 = (uint4*)(kvbase + 4194304);
  unsigned short* wb = (unsigned short*)(w + 51600128);
  int* flag = (int*)(w + 51668352);
  float* Qt = (float*)(w + 51668480);
  float* St = (float*)(w + 77268480);
  const size_t NEED_BIG = 102868480;
  if (ws_size < NEED_BIG) return;

  // wb layout (shorts), per layer l in {0,1} at l*16640:
  //   PQ2 @+0, PK2 @+4096, PV2 @+8192, PS2 @+12288 (pair-packed over k)
  //   bq @+16384, bk @+16448, bv @+16512, bs @+16576
  // layer 3 @33280: W12p pair-packed [32][12] (768 shorts) -> ends 34048;
  //   bq3 @34048, bk3 @34051, bv3 @34054, bs3 @34057 (wb area is 34112 shorts)
  CvtArgs ca;
  {
    int idx = 0;
    for (int l = 0; l < 2; ++l) {
      int base = l * 16640;
      for (int p = 0; p < 4; ++p) {  // p: 0=q,1=k,2=v,3=s
        ca.src[idx] = d_in[3 + l * 8 + p * 2];
        ca.dstoff[idx] = base + p * 4096;
        ca.n[idx] = 4096;
        ca.pp[idx] = 1;
        idx++;
        ca.src[idx] = d_in[3 + l * 8 + p * 2 + 1];
        ca.dstoff[idx] = base + 16384 + p * 64;
        ca.n[idx] = 64;
        ca.pp[idx] = 0;
        idx++;
      }
    }
    for (int p = 0; p < 4; ++p) {  // layer 3: q,k,v,s -> cols 0,3,6,9
      ca.src[idx] = d_in[3 + 16 + p * 2];
      ca.dstoff[idx] = 33280;
      ca.n[idx] = 192;
      ca.pp[idx] = 3 + p * 3;
      idx++;
      ca.src[idx] = d_in[3 + 16 + p * 2 + 1];
      ca.dstoff[idx] = 34048 + p * 3;
      ca.n[idx] = 3;
      ca.pp[idx] = 0;
      idx++;
    }
  }
  const unsigned* PQ20 = (const unsigned*)(wb);
  const unsigned* PK20 = (const unsigned*)(wb + 4096);
  const unsigned* PV20 = (const unsigned*)(wb + 8192);
  const unsigned* PS20 = (const unsigned*)(wb + 12288);
  const unsigned* PQ21 = (const unsigned*)(wb + 16640);
  const unsigned* PK21 = (const unsigned*)(wb + 16640 + 4096);
  const unsigned* PV21 = (const unsigned*)(wb + 16640 + 8192);
  const unsigned* PS21 = (const unsigned*)(wb + 16640 + 12288);
  const unsigned short* Bq0 = wb + 16384;
  const unsigned short* Bk0 = wb + 16448;
  const unsigned short* Bv0 = wb + 16512;
  const unsigned short* Bs0 = wb + 16576;
  const unsigned short* Bq1 = wb + 16640 + 16384;
  const unsigned short* Bk1 = wb + 16640 + 16448;
  const unsigned short* Bv1 = wb + 16640 + 16512;
  const unsigned short* Bs1 = wb + 16640 + 16576;
  const unsigned* W12p = (const unsigned*)(wb + 33280);
  const unsigned short* B3q = wb + 34048;
  const unsigned short* B3k = wb + 34051;
  const unsigned short* B3v = wb + 34054;
  const unsigned short* B3s = wb + 34057;

  k_detect<<<1, 256, 0, stream>>>((const unsigned short*)d_in[0], flag);
  k_cvt_w<<<24, 256, 0, stream>>>(ca, wb, flag);

  // CSR build (uses hreg + kvbase as scratch)
  k_bhist<<<NCHUNK, 256, 0, stream>>>(dsts, counts);
  k_bscanA<<<NBUK, 64, 0, stream>>>(counts, tot);
  k_bscanB<<<1, 512, 0, stream>>>(tot, bbase);
  k_bscat<<<NCHUNK, 256, 0, stream>>>(srcs, dsts, counts, bbase, blist);
  k_bfinal<<<NBUK, 256, 0, stream>>>(blist, bbase, off, csr);

  const int gw = N_NODES / 4;    // 25000 blocks x 4 waves (edge passes, edge3)
  const int gp = N_NODES / 32;   // 3125 blocks: 12500 waves x 8 rows (gemmkvqs)
  const int g3 = (N_NODES + 63) / 64;  // 1563 blocks (gemm3, 16 nodes/wave)
  // layer 1 (reads raw x, converts inline; k_cvt_x removed)
  k_gemmkvqs<true><<<gp, 256, 0, stream>>>(d_in[0], flag, PQ20, PK20, PV20, PS20,
                                           Bq0, Bk0, Bv0, Bs0, Kt, Vt, Qt, St);
  k_edge64b<false><<<gw, 256, 0, stream>>>(off, csr, h, Qt, St, Kt, Vt, h);
  // layer 2
  k_gemmkvqs<false><<<gp, 256, 0, stream>>>(h, flag, PQ21, PK21, PV21, PS21,
                                            Bq1, Bk1, Bv1, Bs1, Kt, Vt, Qt, St);
  k_edge64b<true><<<gw, 256, 0, stream>>>(off, csr, h, Qt, St, Kt, Vt, h);
  // layer 3
  k_gemm3<<<g3, 256, 0, stream>>>(h, W12p, B3q, B3k, B3v, B3s, Q3, S3, KV3);
  k_edge3<<<gw, 256, 0, stream>>>(off, csr, Q3, S3, KV3, d_in[2], d_out, flag);
}